// Round 1
// baseline (12051.624 us; speedup 1.0000x reference)
//
#include <hip/hip_runtime.h>
#include <hip/hip_bf16.h>

#define T_LEN 1024
#define NB    32
#define DD    512
#define HH    512
#define EPS_  1e-5f

typedef unsigned short u16;
typedef unsigned int   u32;
typedef float  f32x16 __attribute__((ext_vector_type(16)));
typedef short  bf16x8 __attribute__((ext_vector_type(8)));

__device__ __forceinline__ u16 f2bf(float f) {
    union { float f; u32 u; } cv; cv.f = f;
    u32 r = cv.u + 0x7FFFu + ((cv.u >> 16) & 1u);   // RNE
    return (u16)(r >> 16);
}
__device__ __forceinline__ float fsig(float x) {
    return 1.0f / (1.0f + __expf(-x));
}
__device__ __forceinline__ float ftanh(float x) {
    float ax = fabsf(x);
    float e  = __expf(-2.0f * ax);
    float t  = (1.0f - e) / (1.0f + e);
    return copysignf(t, x);
}

// ---------------- LayerNorm: x[T,B,D] f32 -> xn bf16 ----------------
__global__ __launch_bounds__(256) void ln_kernel(const float* __restrict__ x,
                                                 const float* __restrict__ gamma,
                                                 const float* __restrict__ beta,
                                                 u16* __restrict__ xn) {
    int wave = threadIdx.x >> 6, lane = threadIdx.x & 63;
    long row = (long)blockIdx.x * 4 + wave;              // 0..T*B-1
    const float* xr = x + row * DD;
    int c0 = lane * 8;
    float4 v0 = *(const float4*)(xr + c0);
    float4 v1 = *(const float4*)(xr + c0 + 4);
    float s = v0.x+v0.y+v0.z+v0.w + v1.x+v1.y+v1.z+v1.w;
    float q = v0.x*v0.x+v0.y*v0.y+v0.z*v0.z+v0.w*v0.w
            + v1.x*v1.x+v1.y*v1.y+v1.z*v1.z+v1.w*v1.w;
    #pragma unroll
    for (int m = 1; m < 64; m <<= 1) { s += __shfl_xor(s, m); q += __shfl_xor(q, m); }
    float mu  = s * (1.0f / DD);
    float var = q * (1.0f / DD) - mu * mu;
    float rs  = rsqrtf(var + EPS_);
    float4 g0 = *(const float4*)(gamma + c0), g1 = *(const float4*)(gamma + c0 + 4);
    float4 b0 = *(const float4*)(beta  + c0), b1 = *(const float4*)(beta  + c0 + 4);
    float o[8];
    o[0]=(v0.x-mu)*rs*g0.x+b0.x; o[1]=(v0.y-mu)*rs*g0.y+b0.y;
    o[2]=(v0.z-mu)*rs*g0.z+b0.z; o[3]=(v0.w-mu)*rs*g0.w+b0.w;
    o[4]=(v1.x-mu)*rs*g1.x+b1.x; o[5]=(v1.y-mu)*rs*g1.y+b1.y;
    o[6]=(v1.z-mu)*rs*g1.z+b1.z; o[7]=(v1.w-mu)*rs*g1.w+b1.w;
    uint4 pk;
    pk.x = (u32)f2bf(o[0]) | ((u32)f2bf(o[1]) << 16);
    pk.y = (u32)f2bf(o[2]) | ((u32)f2bf(o[3]) << 16);
    pk.z = (u32)f2bf(o[4]) | ((u32)f2bf(o[5]) << 16);
    pk.w = (u32)f2bf(o[6]) | ((u32)f2bf(o[7]) << 16);
    *(uint4*)(xn + row * DD + c0) = pk;
}

// ---------------- prep: W->bf16, bias combine, zero out/exchange/flags ----------------
__global__ __launch_bounds__(256) void prep_kernel(
        const float* __restrict__ wih_f, const float* __restrict__ whh_f,
        const float* __restrict__ bih_f, const float* __restrict__ bhh_f,
        const float* __restrict__ wih_b, const float* __restrict__ whh_b,
        const float* __restrict__ bih_b, const float* __restrict__ bhh_b,
        u16* __restrict__ Wc, float* __restrict__ biasC,
        u16* __restrict__ xch, int* __restrict__ flags, float* __restrict__ out) {
    long i0 = (long)blockIdx.x * 256 + threadIdx.x;
    long stride = (long)gridDim.x * 256;
    for (long idx = i0; idx < 16777216L; idx += stride) {
        out[idx] = 0.0f;
        if (idx < 4194304L) {
            int m = (int)(idx >> 20); int off = (int)(idx & 1048575L);
            const float* src = (m == 0) ? wih_f : (m == 1) ? whh_f : (m == 2) ? wih_b : whh_b;
            Wc[idx] = f2bf(src[off]);
        }
        if (idx < 4096L) {
            int d = (int)(idx >> 11), n = (int)(idx & 2047L);
            biasC[idx] = d ? (bih_b[n] + bhh_b[n]) : (bih_f[n] + bhh_f[n]);
        }
        if (idx < 65536L) xch[idx] = 0;
        if (idx < 128L)   flags[idx] = -1;
    }
}

// ---------------- persistent bidirectional LSTM scan ----------------
// 32 blocks: block = (dir<<4)|wg. 8 waves: w0-3 x-waves (gate w), w4-7 h-waves (gate w-4).
// W slices resident in VGPRs as MFMA A-fragments. Per step: x-waves compute gx(t) one step
// ahead (hides the inter-WG flag wait); h-waves do h-matvec + gating + bf16 h exchange.
#define SMEM_BYTES 115200
__global__ __launch_bounds__(512, 2) void scan_kernel(
        const u16* __restrict__ xn, const u16* __restrict__ Wc,
        const float* __restrict__ biasC, u16* __restrict__ xch,
        int* __restrict__ flags, float* __restrict__ out) {
    extern __shared__ char smem_raw[];
    u16*   xn_lds = (u16*)smem_raw;            // [32][512] bf16, swizzled
    u16*   h_lds  = xn_lds + 16384;            // [32][512] bf16, swizzled
    float* accx   = (float*)(h_lds + 16384);   // [2][4][16*64] raw (r,lane)
    float* gatesb = accx + 8192;               // [4][16*64]
    float* bias_l = gatesb + 4096;             // [4][32]

    const int wg   = blockIdx.x & 15;
    const int dir  = blockIdx.x >> 4;
    const int w    = threadIdx.x >> 6;
    const int lane = threadIdx.x & 63;
    const bool is_x = (w < 4);
    const int g    = w & 3;
    int* flg = flags + dir * 64;

    // Resident W fragments: A[row=lane&31][k = kc*16 + (lane>>5)*8 + 0..7]
    bf16x8 afrag[32];
    {
        const u16* Wm = Wc + (size_t)(dir * 2 + (is_x ? 0 : 1)) * (2048 * 512)
                      + (size_t)(g * 512 + wg * 32 + (lane & 31)) * 512 + (lane >> 5) * 8;
        #pragma unroll 32
        for (int kc = 0; kc < 32; kc++) afrag[kc] = *(const bf16x8*)(Wm + kc * 16);
    }
    if (!is_x && lane < 32)
        bias_l[g * 32 + lane] = biasC[dir * 2048 + g * 512 + wg * 32 + lane];

    float c_st[4] = {0.f, 0.f, 0.f, 0.f};
    const int bcol = lane & 31;
    const int hi8  = (lane >> 5) * 8;
    const int swz  = (bcol & 7) << 3;          // u16-unit swizzle
    const int tid4 = (w & 3) * 64 + lane;      // 0..255 within x- or h-group

    __syncthreads();

    #pragma unroll 1
    for (int i = 0; i <= T_LEN + 1; ++i) {
        // ---------------- phase 1 ----------------
        if (is_x) {
            if (i < T_LEN) {
                int tph = dir ? (T_LEN - 1 - i) : i;
                const u16* src = xn + (size_t)tph * (NB * DD);
                #pragma unroll 8
                for (int r = 0; r < 8; r++) {
                    int u = (tid4 + 256 * r) * 8;
                    int b = u >> 9, cu = u & 511;
                    bf16x8 v = *(const bf16x8*)(src + u);
                    *(bf16x8*)(xn_lds + b * 512 + (cu ^ ((b & 7) << 3))) = v;
                }
            }
        } else {
            if (i >= 2) {                       // gating for step sigma=i-2
                int sigma = i - 2;
                float G[4][4];
                #pragma unroll 4
                for (int gg = 0; gg < 4; gg++)
                    #pragma unroll 4
                    for (int ii = 0; ii < 4; ii++)
                        G[gg][ii] = gatesb[gg * 1024 + (4 * g + ii) * 64 + lane];
                int jq = 8 * g + 4 * (lane >> 5);
                int b  = lane & 31;
                float hval[4];
                #pragma unroll 4
                for (int ii = 0; ii < 4; ii++) {
                    float ig  = fsig(G[0][ii]);
                    float fg  = fsig(G[1][ii]);
                    float gg_ = ftanh(G[2][ii]);
                    float og  = fsig(G[3][ii]);
                    float c = fg * c_st[ii] + ig * gg_;
                    c_st[ii] = c;
                    hval[ii] = og * ftanh(c);
                }
                uint2 pk;
                pk.x = (u32)f2bf(hval[0]) | ((u32)f2bf(hval[1]) << 16);
                pk.y = (u32)f2bf(hval[2]) | ((u32)f2bf(hval[3]) << 16);
                u16* slot = xch + (size_t)(dir * 2 + (sigma & 1)) * (NB * HH);
                *(uint2*)(slot + b * HH + wg * 32 + jq) = pk;
                int tph = dir ? (T_LEN - 1 - sigma) : sigma;
                float* op = out + ((size_t)tph * NB + b) * HH + wg * 32 + jq;
                #pragma unroll 4
                for (int ii = 0; ii < 4; ii++) atomicAdd(op + ii, hval[ii]);
                __threadfence();                // release h stores (vmcnt per-wave)
                if (lane == 0)
                    __hip_atomic_store(&flg[wg * 4 + g], sigma,
                                       __ATOMIC_RELAXED, __HIP_MEMORY_SCOPE_AGENT);
            }
            if (i >= 1 && i <= T_LEN) {         // wait + stage h(i-2)
                int tgt = i - 2;
                while (true) {
                    int v = __hip_atomic_load(&flg[lane], __ATOMIC_RELAXED,
                                              __HIP_MEMORY_SCOPE_AGENT);
                    if (__all(v >= tgt)) break;
                    __builtin_amdgcn_s_sleep(2);
                }
                __threadfence();                // acquire
                const u16* slot = xch + (size_t)(dir * 2 + ((i - 2) & 1)) * (NB * HH);
                #pragma unroll 8
                for (int r = 0; r < 8; r++) {
                    int u = (tid4 + 256 * r) * 8;
                    int b = u >> 9, cu = u & 511;
                    bf16x8 v = *(const bf16x8*)(slot + u);
                    *(bf16x8*)(h_lds + b * 512 + (cu ^ ((b & 7) << 3))) = v;
                }
            }
        }
        __syncthreads();
        // ---------------- phase 3 ----------------
        if (is_x) {
            if (i < T_LEN) {
                f32x16 a0, a1;
                #pragma unroll 16
                for (int r = 0; r < 16; r++) { a0[r] = 0.f; a1[r] = 0.f; }
                #pragma unroll 16
                for (int k2 = 0; k2 < 16; k2++) {
                    bf16x8 b0 = *(const bf16x8*)(xn_lds + bcol * 512 + (((2*k2  )*16 + hi8) ^ swz));
                    bf16x8 b1 = *(const bf16x8*)(xn_lds + bcol * 512 + (((2*k2+1)*16 + hi8) ^ swz));
                    a0 = __builtin_amdgcn_mfma_f32_32x32x16_bf16(afrag[2*k2],   b0, a0, 0, 0, 0);
                    a1 = __builtin_amdgcn_mfma_f32_32x32x16_bf16(afrag[2*k2+1], b1, a1, 0, 0, 0);
                }
                float* dst = accx + (i & 1) * 4096 + g * 1024;
                #pragma unroll 16
                for (int r = 0; r < 16; r++) dst[r * 64 + lane] = a0[r] + a1[r];
            }
        } else {
            if (i >= 1 && i <= T_LEN) {
                f32x16 a0, a1;
                #pragma unroll 16
                for (int r = 0; r < 16; r++) { a0[r] = 0.f; a1[r] = 0.f; }
                #pragma unroll 16
                for (int k2 = 0; k2 < 16; k2++) {
                    bf16x8 b0 = *(const bf16x8*)(h_lds + bcol * 512 + (((2*k2  )*16 + hi8) ^ swz));
                    bf16x8 b1 = *(const bf16x8*)(h_lds + bcol * 512 + (((2*k2+1)*16 + hi8) ^ swz));
                    a0 = __builtin_amdgcn_mfma_f32_32x32x16_bf16(afrag[2*k2],   b0, a0, 0, 0, 0);
                    a1 = __builtin_amdgcn_mfma_f32_32x32x16_bf16(afrag[2*k2+1], b1, a1, 0, 0, 0);
                }
                const float* ax = accx + ((i - 1) & 1) * 4096 + g * 1024;
                #pragma unroll 16
                for (int r = 0; r < 16; r++) {
                    int j = (r & 3) + 8 * (r >> 2) + 4 * (lane >> 5);
                    gatesb[g * 1024 + r * 64 + lane] =
                        a0[r] + a1[r] + ax[r * 64 + lane] + bias_l[g * 32 + j];
                }
            }
        }
        __syncthreads();
    }
}

extern "C" void kernel_launch(void* const* d_in, const int* in_sizes, int n_in,
                              void* d_out, int out_size, void* d_ws, size_t ws_size,
                              hipStream_t stream) {
    const float* x     = (const float*)d_in[0];
    const float* gamma = (const float*)d_in[1];
    const float* beta  = (const float*)d_in[2];
    const float* wih_f = (const float*)d_in[3];
    const float* whh_f = (const float*)d_in[4];
    const float* bih_f = (const float*)d_in[5];
    const float* bhh_f = (const float*)d_in[6];
    const float* wih_b = (const float*)d_in[7];
    const float* whh_b = (const float*)d_in[8];
    const float* bih_b = (const float*)d_in[9];
    const float* bhh_b = (const float*)d_in[10];
    float* out = (float*)d_out;

    u16*   xn    = (u16*)d_ws;                  // 16,777,216 u16 = 32MB
    u16*   Wc    = xn + 16777216;               // 4,194,304 u16 = 8MB
    float* biasC = (float*)(Wc + 4194304);      // 4096 f32
    u16*   xch   = (u16*)(biasC + 4096);        // 65536 u16 = 128KB
    int*   flags = (int*)(xch + 65536);         // 128 ints

    (void)hipFuncSetAttribute((const void*)scan_kernel,
                              hipFuncAttributeMaxDynamicSharedMemorySize, SMEM_BYTES);

    ln_kernel<<<dim3(8192), dim3(256), 0, stream>>>(x, gamma, beta, xn);
    prep_kernel<<<dim3(4096), dim3(256), 0, stream>>>(wih_f, whh_f, bih_f, bhh_f,
                                                      wih_b, whh_b, bih_b, bhh_b,
                                                      Wc, biasC, xch, flags, out);
    scan_kernel<<<dim3(32), dim3(512), SMEM_BYTES, stream>>>(xn, Wc, biasC, xch, flags, out);
}

// Round 2
// 9604.734 us; speedup vs baseline: 1.2548x; 1.2548x over previous
//
#include <hip/hip_runtime.h>
#include <hip/hip_bf16.h>

#define T_LEN 1024
#define NB    32
#define DD    512
#define HH    512
#define EPS_  1e-5f

typedef unsigned short u16;
typedef unsigned int   u32;
typedef unsigned long long u64;
typedef float  f32x16 __attribute__((ext_vector_type(16)));
typedef short  bf16x8 __attribute__((ext_vector_type(8)));

__device__ __forceinline__ u16 f2bf(float f) {
    union { float f; u32 u; } cv; cv.f = f;
    u32 r = cv.u + 0x7FFFu + ((cv.u >> 16) & 1u);   // RNE
    return (u16)(r >> 16);
}
__device__ __forceinline__ float fsig(float x) {
    return 1.0f / (1.0f + __expf(-x));
}
__device__ __forceinline__ float ftanh(float x) {
    float ax = fabsf(x);
    float e  = __expf(-2.0f * ax);
    float t  = (1.0f - e) / (1.0f + e);
    return copysignf(t, x);
}

// ---------------- LayerNorm: x[T,B,D] f32 -> xn bf16 ----------------
__global__ __launch_bounds__(256) void ln_kernel(const float* __restrict__ x,
                                                 const float* __restrict__ gamma,
                                                 const float* __restrict__ beta,
                                                 u16* __restrict__ xn) {
    int wave = threadIdx.x >> 6, lane = threadIdx.x & 63;
    long row = (long)blockIdx.x * 4 + wave;              // 0..T*B-1
    const float* xr = x + row * DD;
    int c0 = lane * 8;
    float4 v0 = *(const float4*)(xr + c0);
    float4 v1 = *(const float4*)(xr + c0 + 4);
    float s = v0.x+v0.y+v0.z+v0.w + v1.x+v1.y+v1.z+v1.w;
    float q = v0.x*v0.x+v0.y*v0.y+v0.z*v0.z+v0.w*v0.w
            + v1.x*v1.x+v1.y*v1.y+v1.z*v1.z+v1.w*v1.w;
    #pragma unroll
    for (int m = 1; m < 64; m <<= 1) { s += __shfl_xor(s, m); q += __shfl_xor(q, m); }
    float mu  = s * (1.0f / DD);
    float var = q * (1.0f / DD) - mu * mu;
    float rs  = rsqrtf(var + EPS_);
    float4 g0 = *(const float4*)(gamma + c0), g1 = *(const float4*)(gamma + c0 + 4);
    float4 b0 = *(const float4*)(beta  + c0), b1 = *(const float4*)(beta  + c0 + 4);
    float o[8];
    o[0]=(v0.x-mu)*rs*g0.x+b0.x; o[1]=(v0.y-mu)*rs*g0.y+b0.y;
    o[2]=(v0.z-mu)*rs*g0.z+b0.z; o[3]=(v0.w-mu)*rs*g0.w+b0.w;
    o[4]=(v1.x-mu)*rs*g1.x+b1.x; o[5]=(v1.y-mu)*rs*g1.y+b1.y;
    o[6]=(v1.z-mu)*rs*g1.z+b1.z; o[7]=(v1.w-mu)*rs*g1.w+b1.w;
    uint4 pk;
    pk.x = (u32)f2bf(o[0]) | ((u32)f2bf(o[1]) << 16);
    pk.y = (u32)f2bf(o[2]) | ((u32)f2bf(o[3]) << 16);
    pk.z = (u32)f2bf(o[4]) | ((u32)f2bf(o[5]) << 16);
    pk.w = (u32)f2bf(o[6]) | ((u32)f2bf(o[7]) << 16);
    *(uint4*)(xn + row * DD + c0) = pk;
}

// ---------------- prep: W->bf16, bias combine, zero out/exchange/flags ----------------
__global__ __launch_bounds__(256) void prep_kernel(
        const float* __restrict__ wih_f, const float* __restrict__ whh_f,
        const float* __restrict__ bih_f, const float* __restrict__ bhh_f,
        const float* __restrict__ wih_b, const float* __restrict__ whh_b,
        const float* __restrict__ bih_b, const float* __restrict__ bhh_b,
        u16* __restrict__ Wc, float* __restrict__ biasC,
        u16* __restrict__ xch, int* __restrict__ flags, float* __restrict__ out) {
    long i0 = (long)blockIdx.x * 256 + threadIdx.x;
    long stride = (long)gridDim.x * 256;
    for (long idx = i0; idx < 16777216L; idx += stride) {
        out[idx] = 0.0f;
        if (idx < 4194304L) {
            int m = (int)(idx >> 20); int off = (int)(idx & 1048575L);
            const float* src = (m == 0) ? wih_f : (m == 1) ? whh_f : (m == 2) ? wih_b : whh_b;
            Wc[idx] = f2bf(src[off]);
        }
        if (idx < 4096L) {
            int d = (int)(idx >> 11), n = (int)(idx & 2047L);
            biasC[idx] = d ? (bih_b[n] + bhh_b[n]) : (bih_f[n] + bhh_f[n]);
        }
        if (idx < 65536L) xch[idx] = 0;
        if (idx < 128L)   flags[idx] = -1;
    }
}

// ---------------- persistent bidirectional LSTM scan ----------------
// 32 blocks: block = (dir<<4)|wg. 8 waves: w0-3 x-waves (gate w), w4-7 h-waves (gate w-4).
// W slices resident in VGPRs as MFMA A-fragments. Per step: x-waves compute gx(t) one step
// ahead (hides the inter-WG flag wait); h-waves do h-matvec + gating + bf16 h exchange.
// Cross-WG exchange: RELAXED agent-scope atomics (sc1 -> coherent at LLC, no cache
// maintenance). Release order data->flag via s_waitcnt vmcnt(0) only (no threadfence!).
#define SMEM_BYTES 115200
__global__ __launch_bounds__(512, 2) void scan_kernel(
        const u16* __restrict__ xn, const u16* __restrict__ Wc,
        const float* __restrict__ biasC, u16* __restrict__ xch,
        int* __restrict__ flags, float* __restrict__ out) {
    extern __shared__ char smem_raw[];
    u16*   xn_lds = (u16*)smem_raw;            // [32][512] bf16, swizzled
    u16*   h_lds  = xn_lds + 16384;            // [32][512] bf16, swizzled
    float* accx   = (float*)(h_lds + 16384);   // [2][4][16*64] raw (r,lane)
    float* gatesb = accx + 8192;               // [4][16*64]
    float* bias_l = gatesb + 4096;             // [4][32]

    const int wg   = blockIdx.x & 15;
    const int dir  = blockIdx.x >> 4;
    const int w    = threadIdx.x >> 6;
    const int lane = threadIdx.x & 63;
    const bool is_x = (w < 4);
    const int g    = w & 3;
    int* flg = flags + dir * 64;

    // Resident W fragments: A[row=lane&31][k = kc*16 + (lane>>5)*8 + 0..7]
    bf16x8 afrag[32];
    {
        const u16* Wm = Wc + (size_t)(dir * 2 + (is_x ? 0 : 1)) * (2048 * 512)
                      + (size_t)(g * 512 + wg * 32 + (lane & 31)) * 512 + (lane >> 5) * 8;
        #pragma unroll 32
        for (int kc = 0; kc < 32; kc++) afrag[kc] = *(const bf16x8*)(Wm + kc * 16);
    }
    if (!is_x && lane < 32)
        bias_l[g * 32 + lane] = biasC[dir * 2048 + g * 512 + wg * 32 + lane];

    float c_st[4] = {0.f, 0.f, 0.f, 0.f};
    const int bcol = lane & 31;
    const int hi8  = (lane >> 5) * 8;
    const int swz  = (bcol & 7) << 3;          // u16-unit swizzle
    const int tid4 = (w & 3) * 64 + lane;      // 0..255 within x- or h-group

    __syncthreads();

    #pragma unroll 1
    for (int i = 0; i <= T_LEN + 1; ++i) {
        // ---------------- phase 1 ----------------
        if (is_x) {
            if (i < T_LEN) {
                int tph = dir ? (T_LEN - 1 - i) : i;
                const u16* src = xn + (size_t)tph * (NB * DD);
                #pragma unroll 8
                for (int r = 0; r < 8; r++) {
                    int u = (tid4 + 256 * r) * 8;
                    int b = u >> 9, cu = u & 511;
                    bf16x8 v = *(const bf16x8*)(src + u);
                    *(bf16x8*)(xn_lds + b * 512 + (cu ^ ((b & 7) << 3))) = v;
                }
            }
        } else {
            if (i >= 2) {                       // gating for step sigma=i-2
                int sigma = i - 2;
                float G[4][4];
                #pragma unroll 4
                for (int gg = 0; gg < 4; gg++)
                    #pragma unroll 4
                    for (int ii = 0; ii < 4; ii++)
                        G[gg][ii] = gatesb[gg * 1024 + (4 * g + ii) * 64 + lane];
                int jq = 8 * g + 4 * (lane >> 5);
                int b  = lane & 31;
                float hval[4];
                #pragma unroll 4
                for (int ii = 0; ii < 4; ii++) {
                    float ig  = fsig(G[0][ii]);
                    float fg  = fsig(G[1][ii]);
                    float gg_ = ftanh(G[2][ii]);
                    float og  = fsig(G[3][ii]);
                    float c = fg * c_st[ii] + ig * gg_;
                    c_st[ii] = c;
                    hval[ii] = og * ftanh(c);
                }
                u64 pk;
                pk = (u64)f2bf(hval[0]) | ((u64)f2bf(hval[1]) << 16)
                   | ((u64)f2bf(hval[2]) << 32) | ((u64)f2bf(hval[3]) << 48);
                u16* slot = xch + (size_t)(dir * 2 + (sigma & 1)) * (NB * HH);
                // relaxed agent-scope store -> write-through to LLC (sc1), no fence needed
                __hip_atomic_store((u64*)(slot + b * HH + wg * 32 + jq), pk,
                                   __ATOMIC_RELAXED, __HIP_MEMORY_SCOPE_AGENT);
                int tph = dir ? (T_LEN - 1 - sigma) : sigma;
                float* op = out + ((size_t)tph * NB + b) * HH + wg * 32 + jq;
                #pragma unroll 4
                for (int ii = 0; ii < 4; ii++) atomicAdd(op + ii, hval[ii]);
                // release: all prior vmem (incl. the sc1 h-store) retired -> visible at LLC
                asm volatile("s_waitcnt vmcnt(0)" ::: "memory");
                if (lane == 0)
                    __hip_atomic_store(&flg[wg * 4 + g], sigma,
                                       __ATOMIC_RELAXED, __HIP_MEMORY_SCOPE_AGENT);
            }
            if (i >= 1 && i <= T_LEN) {         // wait + stage h(i-2)
                int tgt = i - 2;
                while (true) {
                    int v = __hip_atomic_load(&flg[lane], __ATOMIC_RELAXED,
                                              __HIP_MEMORY_SCOPE_AGENT);
                    if (__all(v >= tgt)) break;
                }
                const u16* slot = xch + (size_t)(dir * 2 + ((i - 2) & 1)) * (NB * HH);
                #pragma unroll 8
                for (int r = 0; r < 8; r++) {
                    int u = (tid4 + 256 * r) * 8;
                    int b = u >> 9, cu = u & 511;
                    // relaxed agent-scope loads (sc1) -> read from LLC, no invalidate needed
                    u64 lo = __hip_atomic_load((const u64*)(slot + u),
                                               __ATOMIC_RELAXED, __HIP_MEMORY_SCOPE_AGENT);
                    u64 hi = __hip_atomic_load((const u64*)(slot + u + 4),
                                               __ATOMIC_RELAXED, __HIP_MEMORY_SCOPE_AGENT);
                    u16* dst = h_lds + b * 512 + (cu ^ ((b & 7) << 3));
                    *(u64*)(dst)     = lo;
                    *(u64*)(dst + 4) = hi;
                }
            }
        }
        __syncthreads();
        // ---------------- phase 3 ----------------
        if (is_x) {
            if (i < T_LEN) {
                f32x16 a0, a1;
                #pragma unroll 16
                for (int r = 0; r < 16; r++) { a0[r] = 0.f; a1[r] = 0.f; }
                #pragma unroll 16
                for (int k2 = 0; k2 < 16; k2++) {
                    bf16x8 b0 = *(const bf16x8*)(xn_lds + bcol * 512 + (((2*k2  )*16 + hi8) ^ swz));
                    bf16x8 b1 = *(const bf16x8*)(xn_lds + bcol * 512 + (((2*k2+1)*16 + hi8) ^ swz));
                    a0 = __builtin_amdgcn_mfma_f32_32x32x16_bf16(afrag[2*k2],   b0, a0, 0, 0, 0);
                    a1 = __builtin_amdgcn_mfma_f32_32x32x16_bf16(afrag[2*k2+1], b1, a1, 0, 0, 0);
                }
                float* dst = accx + (i & 1) * 4096 + g * 1024;
                #pragma unroll 16
                for (int r = 0; r < 16; r++) dst[r * 64 + lane] = a0[r] + a1[r];
            }
        } else {
            if (i >= 1 && i <= T_LEN) {
                f32x16 a0, a1;
                #pragma unroll 16
                for (int r = 0; r < 16; r++) { a0[r] = 0.f; a1[r] = 0.f; }
                #pragma unroll 16
                for (int k2 = 0; k2 < 16; k2++) {
                    bf16x8 b0 = *(const bf16x8*)(h_lds + bcol * 512 + (((2*k2  )*16 + hi8) ^ swz));
                    bf16x8 b1 = *(const bf16x8*)(h_lds + bcol * 512 + (((2*k2+1)*16 + hi8) ^ swz));
                    a0 = __builtin_amdgcn_mfma_f32_32x32x16_bf16(afrag[2*k2],   b0, a0, 0, 0, 0);
                    a1 = __builtin_amdgcn_mfma_f32_32x32x16_bf16(afrag[2*k2+1], b1, a1, 0, 0, 0);
                }
                const float* ax = accx + ((i - 1) & 1) * 4096 + g * 1024;
                #pragma unroll 16
                for (int r = 0; r < 16; r++) {
                    int j = (r & 3) + 8 * (r >> 2) + 4 * (lane >> 5);
                    gatesb[g * 1024 + r * 64 + lane] =
                        a0[r] + a1[r] + ax[r * 64 + lane] + bias_l[g * 32 + j];
                }
            }
        }
        __syncthreads();
    }
}

extern "C" void kernel_launch(void* const* d_in, const int* in_sizes, int n_in,
                              void* d_out, int out_size, void* d_ws, size_t ws_size,
                              hipStream_t stream) {
    const float* x     = (const float*)d_in[0];
    const float* gamma = (const float*)d_in[1];
    const float* beta  = (const float*)d_in[2];
    const float* wih_f = (const float*)d_in[3];
    const float* whh_f = (const float*)d_in[4];
    const float* bih_f = (const float*)d_in[5];
    const float* bhh_f = (const float*)d_in[6];
    const float* wih_b = (const float*)d_in[7];
    const float* whh_b = (const float*)d_in[8];
    const float* bih_b = (const float*)d_in[9];
    const float* bhh_b = (const float*)d_in[10];
    float* out = (float*)d_out;

    u16*   xn    = (u16*)d_ws;                  // 16,777,216 u16 = 32MB
    u16*   Wc    = xn + 16777216;               // 4,194,304 u16 = 8MB
    float* biasC = (float*)(Wc + 4194304);      // 4096 f32
    u16*   xch   = (u16*)(biasC + 4096);        // 65536 u16 = 128KB
    int*   flags = (int*)(xch + 65536);         // 128 ints

    (void)hipFuncSetAttribute((const void*)scan_kernel,
                              hipFuncAttributeMaxDynamicSharedMemorySize, SMEM_BYTES);

    ln_kernel<<<dim3(8192), dim3(256), 0, stream>>>(x, gamma, beta, xn);
    prep_kernel<<<dim3(4096), dim3(256), 0, stream>>>(wih_f, whh_f, bih_f, bhh_f,
                                                      wih_b, whh_b, bih_b, bhh_b,
                                                      Wc, biasC, xch, flags, out);
    scan_kernel<<<dim3(32), dim3(512), SMEM_BYTES, stream>>>(xn, Wc, biasC, xch, flags, out);
}

// Round 4
// 9139.474 us; speedup vs baseline: 1.3186x; 1.0509x over previous
//
#include <hip/hip_runtime.h>
#include <hip/hip_bf16.h>

#define T_LEN 1024
#define NB    32
#define DD    512
#define HH    512
#define EPS_  1e-5f

typedef unsigned short u16;
typedef unsigned int   u32;
typedef unsigned long long u64;
typedef float  f32x16 __attribute__((ext_vector_type(16)));
typedef short  bf16x8 __attribute__((ext_vector_type(8)));

__device__ __forceinline__ u16 f2bf(float f) {
    union { float f; u32 u; } cv; cv.f = f;
    u32 r = cv.u + 0x7FFFu + ((cv.u >> 16) & 1u);   // RNE
    return (u16)(r >> 16);
}
__device__ __forceinline__ float fsig(float x) {
    return 1.0f / (1.0f + __expf(-x));
}
__device__ __forceinline__ float ftanh(float x) {
    float ax = fabsf(x);
    float e  = __expf(-2.0f * ax);
    float t  = (1.0f - e) / (1.0f + e);
    return copysignf(t, x);
}

// ---------------- LayerNorm: x[T,B,D] f32 -> xn bf16 ----------------
__global__ __launch_bounds__(256) void ln_kernel(const float* __restrict__ x,
                                                 const float* __restrict__ gamma,
                                                 const float* __restrict__ beta,
                                                 u16* __restrict__ xn) {
    int wave = threadIdx.x >> 6, lane = threadIdx.x & 63;
    long row = (long)blockIdx.x * 4 + wave;              // 0..T*B-1
    const float* xr = x + row * DD;
    int c0 = lane * 8;
    float4 v0 = *(const float4*)(xr + c0);
    float4 v1 = *(const float4*)(xr + c0 + 4);
    float s = v0.x+v0.y+v0.z+v0.w + v1.x+v1.y+v1.z+v1.w;
    float q = v0.x*v0.x+v0.y*v0.y+v0.z*v0.z+v0.w*v0.w
            + v1.x*v1.x+v1.y*v1.y+v1.z*v1.z+v1.w*v1.w;
    #pragma unroll
    for (int m = 1; m < 64; m <<= 1) { s += __shfl_xor(s, m); q += __shfl_xor(q, m); }
    float mu  = s * (1.0f / DD);
    float var = q * (1.0f / DD) - mu * mu;
    float rs  = rsqrtf(var + EPS_);
    float4 g0 = *(const float4*)(gamma + c0), g1 = *(const float4*)(gamma + c0 + 4);
    float4 b0 = *(const float4*)(beta  + c0), b1 = *(const float4*)(beta  + c0 + 4);
    float o[8];
    o[0]=(v0.x-mu)*rs*g0.x+b0.x; o[1]=(v0.y-mu)*rs*g0.y+b0.y;
    o[2]=(v0.z-mu)*rs*g0.z+b0.z; o[3]=(v0.w-mu)*rs*g0.w+b0.w;
    o[4]=(v1.x-mu)*rs*g1.x+b1.x; o[5]=(v1.y-mu)*rs*g1.y+b1.y;
    o[6]=(v1.z-mu)*rs*g1.z+b1.z; o[7]=(v1.w-mu)*rs*g1.w+b1.w;
    uint4 pk;
    pk.x = (u32)f2bf(o[0]) | ((u32)f2bf(o[1]) << 16);
    pk.y = (u32)f2bf(o[2]) | ((u32)f2bf(o[3]) << 16);
    pk.z = (u32)f2bf(o[4]) | ((u32)f2bf(o[5]) << 16);
    pk.w = (u32)f2bf(o[6]) | ((u32)f2bf(o[7]) << 16);
    *(uint4*)(xn + row * DD + c0) = pk;
}

// ---------------- prep: W->bf16, bias combine, zero out, init packets ----------------
__global__ __launch_bounds__(256) void prep_kernel(
        const float* __restrict__ wih_f, const float* __restrict__ whh_f,
        const float* __restrict__ bih_f, const float* __restrict__ bhh_f,
        const float* __restrict__ wih_b, const float* __restrict__ whh_b,
        const float* __restrict__ bih_b, const float* __restrict__ bhh_b,
        u16* __restrict__ Wc, float* __restrict__ biasC,
        u64* __restrict__ pkt, float* __restrict__ out) {
    long i0 = (long)blockIdx.x * 256 + threadIdx.x;
    long stride = (long)gridDim.x * 256;
    for (long idx = i0; idx < 16777216L; idx += stride) {
        out[idx] = 0.0f;
        if (idx < 4194304L) {
            int m = (int)(idx >> 20); int off = (int)(idx & 1048575L);
            const float* src = (m == 0) ? wih_f : (m == 1) ? whh_f : (m == 2) ? wih_b : whh_b;
            Wc[idx] = f2bf(src[off]);
        }
        if (idx < 4096L) {
            int d = (int)(idx >> 11), n = (int)(idx & 2047L);
            biasC[idx] = d ? (bih_b[n] + bhh_b[n]) : (bih_f[n] + bhh_f[n]);
        }
        if (idx < 32768L) pkt[idx] = 0xFFFFFFFF00000000ULL;  // h=0, tag=-1
    }
}

// ---------------- persistent bidirectional LSTM scan ----------------
// 32 blocks: block = (dir<<4)|wg. 8 waves: w0-3 x-waves, w4-7 h-waves.
// Cross-WG h exchange: u64 packets {2 x bf16 h, u32 step tag}, relaxed agent-scope
// atomics. One slot = NB*HH/2 = 8192 packets; 2 slots per dir (ring). Readers poll
// the DATA (tag==sigma validates), stage from the validated registers. No flags,
// no fences, no release waits on the critical path.
// out accumulation: x-waves add the staged h(sigma) from h_lds with coalesced
// dword atomicAdds (fire-and-forget, off the recurrence chain).
#define SMEM_BYTES 115200
__global__ __launch_bounds__(512, 2) void scan_kernel(
        const u16* __restrict__ xn, const u16* __restrict__ Wc,
        const float* __restrict__ biasC, u64* __restrict__ pkt,
        float* __restrict__ out) {
    extern __shared__ char smem_raw[];
    u16*   xn_lds = (u16*)smem_raw;            // [32][512] bf16, swizzled
    u16*   h_lds  = xn_lds + 16384;            // [32][512] bf16, swizzled
    float* accx   = (float*)(h_lds + 16384);   // [2][4][16*64] raw (r,lane)
    float* gatesb = accx + 8192;               // [4][16*64]
    float* bias_l = gatesb + 4096;             // [4][32]

    const int wg   = blockIdx.x & 15;
    const int dir  = blockIdx.x >> 4;
    const int w    = threadIdx.x >> 6;
    const int lane = threadIdx.x & 63;
    const bool is_x = (w < 4);
    const int g    = w & 3;

    // Resident W fragments: A[row=lane&31][k = kc*16 + (lane>>5)*8 + 0..7]
    bf16x8 afrag[32];
    {
        const u16* Wm = Wc + (size_t)(dir * 2 + (is_x ? 0 : 1)) * (2048 * 512)
                      + (size_t)(g * 512 + wg * 32 + (lane & 31)) * 512 + (lane >> 5) * 8;
        #pragma unroll 32
        for (int kc = 0; kc < 32; kc++) afrag[kc] = *(const bf16x8*)(Wm + kc * 16);
    }
    if (!is_x && lane < 32)
        bias_l[g * 32 + lane] = biasC[dir * 2048 + g * 512 + wg * 32 + lane];

    float c_st[4] = {0.f, 0.f, 0.f, 0.f};
    const int bcol = lane & 31;
    const int hi8  = (lane >> 5) * 8;
    const int swz  = (bcol & 7) << 3;          // u16-unit swizzle
    const int tid4 = (w & 3) * 64 + lane;      // 0..255 within x- or h-group

    __syncthreads();

    #pragma unroll 1
    for (int i = 0; i <= T_LEN + 1; ++i) {
        // ---------------- phase 1 ----------------
        if (is_x) {
            if (i < T_LEN) {
                int tph = dir ? (T_LEN - 1 - i) : i;
                const u16* src = xn + (size_t)tph * (NB * DD);
                #pragma unroll 8
                for (int r = 0; r < 8; r++) {
                    int u = (tid4 + 256 * r) * 8;
                    int b = u >> 9, cu = u & 511;
                    bf16x8 v = *(const bf16x8*)(src + u);
                    *(bf16x8*)(xn_lds + b * 512 + (cu ^ ((b & 7) << 3))) = v;
                }
            }
        } else {
            if (i >= 2) {                       // gating for step sigma=i-2; publish packets
                int sigma = i - 2;
                float G[4][4];
                #pragma unroll 4
                for (int gg = 0; gg < 4; gg++)
                    #pragma unroll 4
                    for (int ii = 0; ii < 4; ii++)
                        G[gg][ii] = gatesb[gg * 1024 + (4 * g + ii) * 64 + lane];
                int jq = 8 * g + 4 * (lane >> 5);
                int b  = lane & 31;
                float hval[4];
                #pragma unroll 4
                for (int ii = 0; ii < 4; ii++) {
                    float ig  = fsig(G[0][ii]);
                    float fg  = fsig(G[1][ii]);
                    float gg_ = ftanh(G[2][ii]);
                    float og  = fsig(G[3][ii]);
                    float c = fg * c_st[ii] + ig * gg_;
                    c_st[ii] = c;
                    hval[ii] = og * ftanh(c);
                }
                u64 tagw = ((u64)(u32)sigma) << 32;
                u64 p0 = (u64)((u32)f2bf(hval[0]) | ((u32)f2bf(hval[1]) << 16)) | tagw;
                u64 p1 = (u64)((u32)f2bf(hval[2]) | ((u32)f2bf(hval[3]) << 16)) | tagw;
                u64* slot = pkt + (size_t)(dir * 2 + (sigma & 1)) * 8192;
                size_t pi = (size_t)b * 256 + ((wg * 32 + jq) >> 1);
                __hip_atomic_store(slot + pi,     p0, __ATOMIC_RELAXED, __HIP_MEMORY_SCOPE_AGENT);
                __hip_atomic_store(slot + pi + 1, p1, __ATOMIC_RELAXED, __HIP_MEMORY_SCOPE_AGENT);
            }
            if (i >= 1) {                       // poll + stage h(i-2) from validated regs
                u32 tg = (u32)(i - 2);
                const u64* slot = pkt + (size_t)(dir * 2 + ((i - 2) & 1)) * 8192;
                u64 q[8][4];
                while (true) {
                    u32 bad = 0;
                    #pragma unroll 8
                    for (int r = 0; r < 8; r++) {
                        int pb = tid4 * 4 + 1024 * r;
                        #pragma unroll 4
                        for (int k = 0; k < 4; k++)
                            q[r][k] = __hip_atomic_load(slot + pb + k,
                                                        __ATOMIC_RELAXED, __HIP_MEMORY_SCOPE_AGENT);
                    }
                    #pragma unroll 8
                    for (int r = 0; r < 8; r++)
                        #pragma unroll 4
                        for (int k = 0; k < 4; k++)
                            bad |= ((u32)(q[r][k] >> 32)) ^ tg;
                    if (__all(bad == 0)) break;
                }
                #pragma unroll 8
                for (int r = 0; r < 8; r++) {
                    int u = (tid4 + 256 * r) * 8;
                    int b = u >> 9, cu = u & 511;
                    uint4 vv;
                    vv.x = (u32)q[r][0]; vv.y = (u32)q[r][1];
                    vv.z = (u32)q[r][2]; vv.w = (u32)q[r][3];
                    *(uint4*)(h_lds + b * 512 + (cu ^ ((b & 7) << 3))) = vv;
                }
            }
        }
        __syncthreads();
        // ---------------- phase 3 ----------------
        if (is_x) {
            if (i < T_LEN) {
                f32x16 a0, a1;
                #pragma unroll 16
                for (int r = 0; r < 16; r++) { a0[r] = 0.f; a1[r] = 0.f; }
                #pragma unroll 16
                for (int k2 = 0; k2 < 16; k2++) {
                    bf16x8 b0 = *(const bf16x8*)(xn_lds + bcol * 512 + (((2*k2  )*16 + hi8) ^ swz));
                    bf16x8 b1 = *(const bf16x8*)(xn_lds + bcol * 512 + (((2*k2+1)*16 + hi8) ^ swz));
                    a0 = __builtin_amdgcn_mfma_f32_32x32x16_bf16(afrag[2*k2],   b0, a0, 0, 0, 0);
                    a1 = __builtin_amdgcn_mfma_f32_32x32x16_bf16(afrag[2*k2+1], b1, a1, 0, 0, 0);
                }
                float* dst = accx + (i & 1) * 4096 + g * 1024;
                #pragma unroll 16
                for (int r = 0; r < 16; r++) dst[r * 64 + lane] = a0[r] + a1[r];
            }
            if (i >= 2) {                       // out += h(i-2) from h_lds (coalesced atomics)
                int sigma = i - 2;
                int tph = dir ? (T_LEN - 1 - sigma) : sigma;
                float* orow = out + (size_t)tph * (NB * HH);
                #pragma unroll 4
                for (int qq = 0; qq < 4; qq++) {
                    int idx = qq * 256 + tid4;          // 0..1023
                    int b2  = 2 * wg + (idx >> 9);
                    int j   = idx & 511;
                    int cu  = j & ~7, e = j & 7;
                    u16 hv = h_lds[b2 * 512 + ((cu ^ ((b2 & 7) << 3)) | e)];
                    float f = __uint_as_float((u32)hv << 16);
                    atomicAdd(orow + (size_t)b2 * HH + j, f);
                }
            }
        } else {
            if (i >= 1 && i <= T_LEN) {
                f32x16 a0, a1;
                #pragma unroll 16
                for (int r = 0; r < 16; r++) { a0[r] = 0.f; a1[r] = 0.f; }
                #pragma unroll 16
                for (int k2 = 0; k2 < 16; k2++) {
                    bf16x8 b0 = *(const bf16x8*)(h_lds + bcol * 512 + (((2*k2  )*16 + hi8) ^ swz));
                    bf16x8 b1 = *(const bf16x8*)(h_lds + bcol * 512 + (((2*k2+1)*16 + hi8) ^ swz));
                    a0 = __builtin_amdgcn_mfma_f32_32x32x16_bf16(afrag[2*k2],   b0, a0, 0, 0, 0);
                    a1 = __builtin_amdgcn_mfma_f32_32x32x16_bf16(afrag[2*k2+1], b1, a1, 0, 0, 0);
                }
                const float* ax = accx + ((i - 1) & 1) * 4096 + g * 1024;
                #pragma unroll 16
                for (int r = 0; r < 16; r++) {
                    int j = (r & 3) + 8 * (r >> 2) + 4 * (lane >> 5);
                    gatesb[g * 1024 + r * 64 + lane] =
                        a0[r] + a1[r] + ax[r * 64 + lane] + bias_l[g * 32 + j];
                }
            }
        }
        __syncthreads();
    }
}

extern "C" void kernel_launch(void* const* d_in, const int* in_sizes, int n_in,
                              void* d_out, int out_size, void* d_ws, size_t ws_size,
                              hipStream_t stream) {
    const float* x     = (const float*)d_in[0];
    const float* gamma = (const float*)d_in[1];
    const float* beta  = (const float*)d_in[2];
    const float* wih_f = (const float*)d_in[3];
    const float* whh_f = (const float*)d_in[4];
    const float* bih_f = (const float*)d_in[5];
    const float* bhh_f = (const float*)d_in[6];
    const float* wih_b = (const float*)d_in[7];
    const float* whh_b = (const float*)d_in[8];
    const float* bih_b = (const float*)d_in[9];
    const float* bhh_b = (const float*)d_in[10];
    float* out = (float*)d_out;

    u16*   xn    = (u16*)d_ws;                  // 16,777,216 u16 = 32MB
    u16*   Wc    = xn + 16777216;               // 4,194,304 u16 = 8MB
    float* biasC = (float*)(Wc + 4194304);      // 4096 f32
    u64*   pkt   = (u64*)(biasC + 4096);        // 32768 u64 = 256KB (2 dir x 2 slot x 8192)

    (void)hipFuncSetAttribute((const void*)scan_kernel,
                              hipFuncAttributeMaxDynamicSharedMemorySize, SMEM_BYTES);

    ln_kernel<<<dim3(8192), dim3(256), 0, stream>>>(x, gamma, beta, xn);
    prep_kernel<<<dim3(4096), dim3(256), 0, stream>>>(wih_f, whh_f, bih_f, bhh_f,
                                                      wih_b, whh_b, bih_b, bhh_b,
                                                      Wc, biasC, pkt, out);
    scan_kernel<<<dim3(32), dim3(512), SMEM_BYTES, stream>>>(xn, Wc, biasC, pkt, out);
}

// Round 5
// 8645.496 us; speedup vs baseline: 1.3940x; 1.0571x over previous
//
#include <hip/hip_runtime.h>
#include <hip/hip_bf16.h>

#define T_LEN 1024
#define NB    32
#define DD    512
#define HH    512
#define EPS_  1e-5f

typedef unsigned short u16;
typedef unsigned int   u32;
typedef unsigned long long u64;
typedef float  f32x16 __attribute__((ext_vector_type(16)));
typedef short  bf16x8 __attribute__((ext_vector_type(8)));

__device__ __forceinline__ u16 f2bf(float f) {
    union { float f; u32 u; } cv; cv.f = f;
    u32 r = cv.u + 0x7FFFu + ((cv.u >> 16) & 1u);   // RNE
    return (u16)(r >> 16);
}
__device__ __forceinline__ float fsig(float x) {
    return 1.0f / (1.0f + __expf(-x));
}
__device__ __forceinline__ float ftanh(float x) {
    float ax = fabsf(x);
    float e  = __expf(-2.0f * ax);
    float t  = (1.0f - e) / (1.0f + e);
    return copysignf(t, x);
}

// ---------------- LayerNorm: x[T,B,D] f32 -> xn bf16 ----------------
__global__ __launch_bounds__(256) void ln_kernel(const float* __restrict__ x,
                                                 const float* __restrict__ gamma,
                                                 const float* __restrict__ beta,
                                                 u16* __restrict__ xn) {
    int wave = threadIdx.x >> 6, lane = threadIdx.x & 63;
    long row = (long)blockIdx.x * 4 + wave;              // 0..T*B-1
    const float* xr = x + row * DD;
    int c0 = lane * 8;
    float4 v0 = *(const float4*)(xr + c0);
    float4 v1 = *(const float4*)(xr + c0 + 4);
    float s = v0.x+v0.y+v0.z+v0.w + v1.x+v1.y+v1.z+v1.w;
    float q = v0.x*v0.x+v0.y*v0.y+v0.z*v0.z+v0.w*v0.w
            + v1.x*v1.x+v1.y*v1.y+v1.z*v1.z+v1.w*v1.w;
    #pragma unroll
    for (int m = 1; m < 64; m <<= 1) { s += __shfl_xor(s, m); q += __shfl_xor(q, m); }
    float mu  = s * (1.0f / DD);
    float var = q * (1.0f / DD) - mu * mu;
    float rs  = rsqrtf(var + EPS_);
    float4 g0 = *(const float4*)(gamma + c0), g1 = *(const float4*)(gamma + c0 + 4);
    float4 b0 = *(const float4*)(beta  + c0), b1 = *(const float4*)(beta  + c0 + 4);
    float o[8];
    o[0]=(v0.x-mu)*rs*g0.x+b0.x; o[1]=(v0.y-mu)*rs*g0.y+b0.y;
    o[2]=(v0.z-mu)*rs*g0.z+b0.z; o[3]=(v0.w-mu)*rs*g0.w+b0.w;
    o[4]=(v1.x-mu)*rs*g1.x+b1.x; o[5]=(v1.y-mu)*rs*g1.y+b1.y;
    o[6]=(v1.z-mu)*rs*g1.z+b1.z; o[7]=(v1.w-mu)*rs*g1.w+b1.w;
    uint4 pk;
    pk.x = (u32)f2bf(o[0]) | ((u32)f2bf(o[1]) << 16);
    pk.y = (u32)f2bf(o[2]) | ((u32)f2bf(o[3]) << 16);
    pk.z = (u32)f2bf(o[4]) | ((u32)f2bf(o[5]) << 16);
    pk.w = (u32)f2bf(o[6]) | ((u32)f2bf(o[7]) << 16);
    *(uint4*)(xn + row * DD + c0) = pk;
}

// ---------------- prep: W->bf16, bias combine, init packets (+zero out in plan B) ----
__global__ __launch_bounds__(256) void prep_kernel(
        const float* __restrict__ wih_f, const float* __restrict__ whh_f,
        const float* __restrict__ bih_f, const float* __restrict__ bhh_f,
        const float* __restrict__ wih_b, const float* __restrict__ whh_b,
        const float* __restrict__ bih_b, const float* __restrict__ bhh_b,
        u16* __restrict__ Wc, float* __restrict__ biasC,
        u64* __restrict__ pkt, float* __restrict__ out, int zero_out) {
    long i0 = (long)blockIdx.x * 256 + threadIdx.x;
    long stride = (long)gridDim.x * 256;
    long lim = zero_out ? 16777216L : 4194304L;
    for (long idx = i0; idx < lim; idx += stride) {
        if (zero_out) out[idx] = 0.0f;
        if (idx < 4194304L) {
            int m = (int)(idx >> 20); int off = (int)(idx & 1048575L);
            const float* src = (m == 0) ? wih_f : (m == 1) ? whh_f : (m == 2) ? wih_b : whh_b;
            Wc[idx] = f2bf(src[off]);
        }
        if (idx < 4096L) {
            int d = (int)(idx >> 11), n = (int)(idx & 2047L);
            biasC[idx] = d ? (bih_b[n] + bhh_b[n]) : (bih_f[n] + bhh_f[n]);
        }
        if (idx < 32768L) pkt[idx] = 0xFFFFFFFF00000000ULL;  // h=0, tag=-1
    }
}

// ---------------- epilogue: out += bf16(hist_b) ----------------
__global__ __launch_bounds__(256) void add_kernel(float* __restrict__ out,
                                                  const u16* __restrict__ hist) {
    long i0 = (long)blockIdx.x * 256 + threadIdx.x;
    long stride = (long)gridDim.x * 256;
    const ushort4* h4 = (const ushort4*)hist;
    float4* o4 = (float4*)out;
    for (long i = i0; i < 4194304L; i += stride) {
        float4 o = o4[i];
        ushort4 h = h4[i];
        o.x += __uint_as_float((u32)h.x << 16);
        o.y += __uint_as_float((u32)h.y << 16);
        o.z += __uint_as_float((u32)h.z << 16);
        o.w += __uint_as_float((u32)h.w << 16);
        o4[i] = o;
    }
}

// ---------------- persistent bidirectional LSTM scan ----------------
// 32 blocks: block = (dir<<4)|wg. 8 waves: w0-3 x-waves, w4-7 h-waves.
// Cross-WG h exchange: u64 packets {2 x bf16 h, u32 step tag}, relaxed agent-scope
// atomics; 2-slot ring per dir; readers poll the data (tag==sigma validates).
// Output path (plan A, hist != nullptr): NO atomics in this kernel. Fwd WGs write
// their out[t] b-rows with plain f32 stores; bwd WGs write bf16 hist; epilogue adds.
// Plan B (hist == nullptr): R3 behavior (atomicAdd into zeroed out).
#define SMEM_BYTES 115200
__global__ __launch_bounds__(512, 2) void scan_kernel(
        const u16* __restrict__ xn, const u16* __restrict__ Wc,
        const float* __restrict__ biasC, u64* __restrict__ pkt,
        float* __restrict__ out, u16* __restrict__ hist) {
    extern __shared__ char smem_raw[];
    u16*   xn_lds = (u16*)smem_raw;            // [32][512] bf16, swizzled
    u16*   h_lds  = xn_lds + 16384;            // [32][512] bf16, swizzled
    float* accx   = (float*)(h_lds + 16384);   // [2][4][16*64] raw (r,lane)
    float* gatesb = accx + 8192;               // [4][16*64]
    float* bias_l = gatesb + 4096;             // [4][32]

    const int wg   = blockIdx.x & 15;
    const int dir  = blockIdx.x >> 4;
    const int w    = threadIdx.x >> 6;
    const int lane = threadIdx.x & 63;
    const bool is_x = (w < 4);
    const int g    = w & 3;

    // Resident W fragments: A[row=lane&31][k = kc*16 + (lane>>5)*8 + 0..7]
    bf16x8 afrag[32];
    {
        const u16* Wm = Wc + (size_t)(dir * 2 + (is_x ? 0 : 1)) * (2048 * 512)
                      + (size_t)(g * 512 + wg * 32 + (lane & 31)) * 512 + (lane >> 5) * 8;
        #pragma unroll 32
        for (int kc = 0; kc < 32; kc++) afrag[kc] = *(const bf16x8*)(Wm + kc * 16);
    }
    if (!is_x && lane < 32)
        bias_l[g * 32 + lane] = biasC[dir * 2048 + g * 512 + wg * 32 + lane];

    float c_st[4] = {0.f, 0.f, 0.f, 0.f};
    const int bcol = lane & 31;
    const int hi8  = (lane >> 5) * 8;
    const int swz  = (bcol & 7) << 3;          // u16-unit swizzle
    const int tid4 = (w & 3) * 64 + lane;      // 0..255 within x- or h-group

    __syncthreads();

    #pragma unroll 1
    for (int i = 0; i <= T_LEN + 1; ++i) {
        // ---------------- phase 1 ----------------
        if (is_x) {
            if (i < T_LEN) {
                int tph = dir ? (T_LEN - 1 - i) : i;
                const u16* src = xn + (size_t)tph * (NB * DD);
                #pragma unroll 8
                for (int r = 0; r < 8; r++) {
                    int u = (tid4 + 256 * r) * 8;
                    int b = u >> 9, cu = u & 511;
                    bf16x8 v = *(const bf16x8*)(src + u);
                    *(bf16x8*)(xn_lds + b * 512 + (cu ^ ((b & 7) << 3))) = v;
                }
            }
        } else {
            if (i >= 2) {                       // gating for step sigma=i-2; publish packets
                int sigma = i - 2;
                float G[4][4];
                #pragma unroll 4
                for (int gg = 0; gg < 4; gg++)
                    #pragma unroll 4
                    for (int ii = 0; ii < 4; ii++)
                        G[gg][ii] = gatesb[gg * 1024 + (4 * g + ii) * 64 + lane];
                int jq = 8 * g + 4 * (lane >> 5);
                int b  = lane & 31;
                float hval[4];
                #pragma unroll 4
                for (int ii = 0; ii < 4; ii++) {
                    float ig  = fsig(G[0][ii]);
                    float fg  = fsig(G[1][ii]);
                    float gg_ = ftanh(G[2][ii]);
                    float og  = fsig(G[3][ii]);
                    float c = fg * c_st[ii] + ig * gg_;
                    c_st[ii] = c;
                    hval[ii] = og * ftanh(c);
                }
                u64 tagw = ((u64)(u32)sigma) << 32;
                u64 p0 = (u64)((u32)f2bf(hval[0]) | ((u32)f2bf(hval[1]) << 16)) | tagw;
                u64 p1 = (u64)((u32)f2bf(hval[2]) | ((u32)f2bf(hval[3]) << 16)) | tagw;
                u64* slot = pkt + (size_t)(dir * 2 + (sigma & 1)) * 8192;
                size_t pi = (size_t)b * 256 + ((wg * 32 + jq) >> 1);
                __hip_atomic_store(slot + pi,     p0, __ATOMIC_RELAXED, __HIP_MEMORY_SCOPE_AGENT);
                __hip_atomic_store(slot + pi + 1, p1, __ATOMIC_RELAXED, __HIP_MEMORY_SCOPE_AGENT);
            }
            if (i >= 1) {                       // poll + stage h(i-2) from validated regs
                u32 tg = (u32)(i - 2);
                const u64* slot = pkt + (size_t)(dir * 2 + ((i - 2) & 1)) * 8192;
                u64 q[8][4];
                while (true) {
                    u32 bad = 0;
                    #pragma unroll 8
                    for (int r = 0; r < 8; r++) {
                        int pb = tid4 * 4 + 1024 * r;
                        #pragma unroll 4
                        for (int k = 0; k < 4; k++)
                            q[r][k] = __hip_atomic_load(slot + pb + k,
                                                        __ATOMIC_RELAXED, __HIP_MEMORY_SCOPE_AGENT);
                    }
                    #pragma unroll 8
                    for (int r = 0; r < 8; r++)
                        #pragma unroll 4
                        for (int k = 0; k < 4; k++)
                            bad |= ((u32)(q[r][k] >> 32)) ^ tg;
                    if (__all(bad == 0)) break;
                }
                #pragma unroll 8
                for (int r = 0; r < 8; r++) {
                    int u = (tid4 + 256 * r) * 8;
                    int b = u >> 9, cu = u & 511;
                    uint4 vv;
                    vv.x = (u32)q[r][0]; vv.y = (u32)q[r][1];
                    vv.z = (u32)q[r][2]; vv.w = (u32)q[r][3];
                    *(uint4*)(h_lds + b * 512 + (cu ^ ((b & 7) << 3))) = vv;
                }
            }
        }
        __syncthreads();
        // ---------------- phase 3 ----------------
        if (is_x) {
            if (i < T_LEN) {
                f32x16 a0, a1;
                #pragma unroll 16
                for (int r = 0; r < 16; r++) { a0[r] = 0.f; a1[r] = 0.f; }
                #pragma unroll 16
                for (int k2 = 0; k2 < 16; k2++) {
                    bf16x8 b0 = *(const bf16x8*)(xn_lds + bcol * 512 + (((2*k2  )*16 + hi8) ^ swz));
                    bf16x8 b1 = *(const bf16x8*)(xn_lds + bcol * 512 + (((2*k2+1)*16 + hi8) ^ swz));
                    a0 = __builtin_amdgcn_mfma_f32_32x32x16_bf16(afrag[2*k2],   b0, a0, 0, 0, 0);
                    a1 = __builtin_amdgcn_mfma_f32_32x32x16_bf16(afrag[2*k2+1], b1, a1, 0, 0, 0);
                }
                float* dst = accx + (i & 1) * 4096 + g * 1024;
                #pragma unroll 16
                for (int r = 0; r < 16; r++) dst[r * 64 + lane] = a0[r] + a1[r];
            }
            if (i >= 2) {                       // out/hist writes for h(i-2) from h_lds
                int sigma = i - 2;
                int tph = dir ? (T_LEN - 1 - sigma) : sigma;
                if (hist) {
                    if (dir == 0) {             // fwd: plain f32 stores into out
                        float* orow = out + (size_t)tph * (NB * HH);
                        #pragma unroll 4
                        for (int qq = 0; qq < 4; qq++) {
                            int idx = qq * 256 + tid4;          // 0..1023
                            int b2  = 2 * wg + (idx >> 9);
                            int j   = idx & 511;
                            int cu  = j & ~7, e = j & 7;
                            u16 hv = h_lds[b2 * 512 + ((cu ^ ((b2 & 7) << 3)) | e)];
                            orow[(size_t)b2 * HH + j] = __uint_as_float((u32)hv << 16);
                        }
                    } else {                    // bwd: packed bf16 stores into hist
                        u16* hrow = hist + (size_t)tph * (NB * HH);
                        #pragma unroll 2
                        for (int qq = 0; qq < 2; qq++) {
                            int p  = qq * 256 + tid4;           // 0..511 (u32 pairs)
                            int b2 = 2 * wg + (p >> 8);
                            int j0 = (p * 2) & 511;
                            int cu = j0 & ~7, e0 = j0 & 7;
                            u32 v = *(const u32*)&h_lds[b2 * 512 + ((cu ^ ((b2 & 7) << 3)) | e0)];
                            *(u32*)&hrow[(size_t)b2 * HH + j0] = v;
                        }
                    }
                } else {                        // plan B: atomics (R3 path)
                    float* orow = out + (size_t)tph * (NB * HH);
                    #pragma unroll 4
                    for (int qq = 0; qq < 4; qq++) {
                        int idx = qq * 256 + tid4;
                        int b2  = 2 * wg + (idx >> 9);
                        int j   = idx & 511;
                        int cu  = j & ~7, e = j & 7;
                        u16 hv = h_lds[b2 * 512 + ((cu ^ ((b2 & 7) << 3)) | e)];
                        float f = __uint_as_float((u32)hv << 16);
                        atomicAdd(orow + (size_t)b2 * HH + j, f);
                    }
                }
            }
        } else {
            if (i >= 1 && i <= T_LEN) {
                f32x16 a0, a1;
                #pragma unroll 16
                for (int r = 0; r < 16; r++) { a0[r] = 0.f; a1[r] = 0.f; }
                #pragma unroll 16
                for (int k2 = 0; k2 < 16; k2++) {
                    bf16x8 b0 = *(const bf16x8*)(h_lds + bcol * 512 + (((2*k2  )*16 + hi8) ^ swz));
                    bf16x8 b1 = *(const bf16x8*)(h_lds + bcol * 512 + (((2*k2+1)*16 + hi8) ^ swz));
                    a0 = __builtin_amdgcn_mfma_f32_32x32x16_bf16(afrag[2*k2],   b0, a0, 0, 0, 0);
                    a1 = __builtin_amdgcn_mfma_f32_32x32x16_bf16(afrag[2*k2+1], b1, a1, 0, 0, 0);
                }
                const float* ax = accx + ((i - 1) & 1) * 4096 + g * 1024;
                #pragma unroll 16
                for (int r = 0; r < 16; r++) {
                    int j = (r & 3) + 8 * (r >> 2) + 4 * (lane >> 5);
                    gatesb[g * 1024 + r * 64 + lane] =
                        a0[r] + a1[r] + ax[r * 64 + lane] + bias_l[g * 32 + j];
                }
            }
        }
        __syncthreads();
    }
}

extern "C" void kernel_launch(void* const* d_in, const int* in_sizes, int n_in,
                              void* d_out, int out_size, void* d_ws, size_t ws_size,
                              hipStream_t stream) {
    const float* x     = (const float*)d_in[0];
    const float* gamma = (const float*)d_in[1];
    const float* beta  = (const float*)d_in[2];
    const float* wih_f = (const float*)d_in[3];
    const float* whh_f = (const float*)d_in[4];
    const float* bih_f = (const float*)d_in[5];
    const float* bhh_f = (const float*)d_in[6];
    const float* wih_b = (const float*)d_in[7];
    const float* whh_b = (const float*)d_in[8];
    const float* bih_b = (const float*)d_in[9];
    const float* bhh_b = (const float*)d_in[10];
    float* out = (float*)d_out;

    u16*   xn    = (u16*)d_ws;                  // 16,777,216 u16 = 32MB
    u16*   Wc    = xn + 16777216;               // 4,194,304 u16 = 8MB
    float* biasC = (float*)(Wc + 4194304);      // 4096 f32 = 16KB
    u64*   pkt   = (u64*)(biasC + 4096);        // 32768 u64 = 256KB
    u16*   hist  = (u16*)(pkt + 32768);         // 16,777,216 u16 = 32MB (plan A only)

    const size_t NEEDED = 33554432UL + 8388608UL + 16384UL + 262144UL + 33554432UL;
    bool planA = ws_size >= NEEDED;
    u16* hist_arg = planA ? hist : nullptr;

    (void)hipFuncSetAttribute((const void*)scan_kernel,
                              hipFuncAttributeMaxDynamicSharedMemorySize, SMEM_BYTES);

    ln_kernel<<<dim3(8192), dim3(256), 0, stream>>>(x, gamma, beta, xn);
    prep_kernel<<<dim3(4096), dim3(256), 0, stream>>>(wih_f, whh_f, bih_f, bhh_f,
                                                      wih_b, whh_b, bih_b, bhh_b,
                                                      Wc, biasC, pkt, out, planA ? 0 : 1);
    scan_kernel<<<dim3(32), dim3(512), SMEM_BYTES, stream>>>(xn, Wc, biasC, pkt, out, hist_arg);
    if (planA)
        add_kernel<<<dim3(2048), dim3(256), 0, stream>>>(out, hist);
}

// Round 8
// 7681.834 us; speedup vs baseline: 1.5688x; 1.1254x over previous
//
#include <hip/hip_runtime.h>
#include <hip/hip_bf16.h>

#define T_LEN 1024
#define NB    32
#define DD    512
#define HH    512
#define EPS_  1e-5f

typedef unsigned short u16;
typedef unsigned int   u32;
typedef unsigned long long u64;
typedef float  f32x16 __attribute__((ext_vector_type(16)));
typedef short  bf16x8 __attribute__((ext_vector_type(8)));

__device__ __forceinline__ u16 f2bf(float f) {
    union { float f; u32 u; } cv; cv.f = f;
    u32 r = cv.u + 0x7FFFu + ((cv.u >> 16) & 1u);   // RNE
    return (u16)(r >> 16);
}
__device__ __forceinline__ float fsig(float x) {
    return 1.0f / (1.0f + __expf(-x));
}
__device__ __forceinline__ float ftanh(float x) {
    float ax = fabsf(x);
    float e  = __expf(-2.0f * ax);
    float t  = (1.0f - e) / (1.0f + e);
    return copysignf(t, x);
}

// ---------------- LayerNorm: x[T,B,D] f32 -> xn bf16 ----------------
__global__ __launch_bounds__(256) void ln_kernel(const float* __restrict__ x,
                                                 const float* __restrict__ gamma,
                                                 const float* __restrict__ beta,
                                                 u16* __restrict__ xn) {
    int wave = threadIdx.x >> 6, lane = threadIdx.x & 63;
    long row = (long)blockIdx.x * 4 + wave;              // 0..T*B-1
    const float* xr = x + row * DD;
    int c0 = lane * 8;
    float4 v0 = *(const float4*)(xr + c0);
    float4 v1 = *(const float4*)(xr + c0 + 4);
    float s = v0.x+v0.y+v0.z+v0.w + v1.x+v1.y+v1.z+v1.w;
    float q = v0.x*v0.x+v0.y*v0.y+v0.z*v0.z+v0.w*v0.w
            + v1.x*v1.x+v1.y*v1.y+v1.z*v1.z+v1.w*v1.w;
    #pragma unroll
    for (int m = 1; m < 64; m <<= 1) { s += __shfl_xor(s, m); q += __shfl_xor(q, m); }
    float mu  = s * (1.0f / DD);
    float var = q * (1.0f / DD) - mu * mu;
    float rs  = rsqrtf(var + EPS_);
    float4 g0 = *(const float4*)(gamma + c0), g1 = *(const float4*)(gamma + c0 + 4);
    float4 b0 = *(const float4*)(beta  + c0), b1 = *(const float4*)(beta  + c0 + 4);
    float o[8];
    o[0]=(v0.x-mu)*rs*g0.x+b0.x; o[1]=(v0.y-mu)*rs*g0.y+b0.y;
    o[2]=(v0.z-mu)*rs*g0.z+b0.z; o[3]=(v0.w-mu)*rs*g0.w+b0.w;
    o[4]=(v1.x-mu)*rs*g1.x+b1.x; o[5]=(v1.y-mu)*rs*g1.y+b1.y;
    o[6]=(v1.z-mu)*rs*g1.z+b1.z; o[7]=(v1.w-mu)*rs*g1.w+b1.w;
    uint4 pk;
    pk.x = (u32)f2bf(o[0]) | ((u32)f2bf(o[1]) << 16);
    pk.y = (u32)f2bf(o[2]) | ((u32)f2bf(o[3]) << 16);
    pk.z = (u32)f2bf(o[4]) | ((u32)f2bf(o[5]) << 16);
    pk.w = (u32)f2bf(o[6]) | ((u32)f2bf(o[7]) << 16);
    *(uint4*)(xn + row * DD + c0) = pk;
}

// ---------------- prep: W->bf16, bias combine, init data+sentinels ----------------
__global__ __launch_bounds__(256) void prep_kernel(
        const float* __restrict__ wih_f, const float* __restrict__ whh_f,
        const float* __restrict__ bih_f, const float* __restrict__ bhh_f,
        const float* __restrict__ wih_b, const float* __restrict__ whh_b,
        const float* __restrict__ bih_b, const float* __restrict__ bhh_b,
        u16* __restrict__ Wc, float* __restrict__ biasC,
        u64* __restrict__ data, int* __restrict__ sent) {
    long i0 = (long)blockIdx.x * 256 + threadIdx.x;
    long stride = (long)gridDim.x * 256;
    for (long idx = i0; idx < 4194304L; idx += stride) {
        int m = (int)(idx >> 20); int off = (int)(idx & 1048575L);
        const float* src = (m == 0) ? wih_f : (m == 1) ? whh_f : (m == 2) ? wih_b : whh_b;
        Wc[idx] = f2bf(src[off]);
        if (idx < 4096L) {
            int d = (int)(idx >> 11), n = (int)(idx & 2047L);
            biasC[idx] = d ? (bih_b[n] + bhh_b[n]) : (bih_f[n] + bhh_f[n]);
        }
        if (idx < 16384L) data[idx] = 0;                   // h = 0
        if (idx < 128L)   sent[idx] = -1;                  // MUST reset each call (replays)
    }
}

// ---------------- epilogue: out += bf16(hist_b) ----------------
__global__ __launch_bounds__(256) void add_kernel(float* __restrict__ out,
                                                  const u16* __restrict__ hist) {
    long i0 = (long)blockIdx.x * 256 + threadIdx.x;
    long stride = (long)gridDim.x * 256;
    const ushort4* h4 = (const ushort4*)hist;
    float4* o4 = (float4*)out;
    for (long i = i0; i < 4194304L; i += stride) {
        float4 o = o4[i];
        ushort4 h = h4[i];
        o.x += __uint_as_float((u32)h.x << 16);
        o.y += __uint_as_float((u32)h.y << 16);
        o.z += __uint_as_float((u32)h.z << 16);
        o.w += __uint_as_float((u32)h.w << 16);
        o4[i] = o;
    }
}

// ---------------- persistent bidirectional LSTM scan ----------------
// 32 blocks: block = (dir<<4)|wg (proven R4 teams, agent-scope MALL exchange).
// 8 waves: w0-3 x-waves, w4-7 h-waves. A-fragment rows REMAPPED so each h-wave owns
// 8 j-columns x all 4 gate types: row r <-> W row (r>>3)*512 + wg*32 + g*8 + (r&7).
// With C/D layout row=(reg&3)+8*(reg>>2)+4*hi, each lane holds gates q=reg>>2 for
// jj=(reg&3)+4*hi, col b=lane&31 -> gate+c-update+publish ALL in registers right after
// the matvec (no LDS gates round-trip, one barrier fewer on the chain).
// Exchange data layout [j/4][b] u64 -> publish = 2x256B contiguous per wave; readers
// bulk-load once. Only h-wave g0 polls sentinels (s_sleep backoff); g1-3 spin on LDS.
#define SMEM_BYTES 98320
__global__ __launch_bounds__(512, 2) void scan_kernel(
        const u16* __restrict__ xn, const u16* __restrict__ Wc,
        const float* __restrict__ biasC, u64* __restrict__ data,
        int* __restrict__ sent, float* __restrict__ out, u16* __restrict__ hist) {
    extern __shared__ char smem_raw[];
    u16*   xn_lds = (u16*)smem_raw;            // [32][512] bf16, swizzled
    u16*   h_lds  = xn_lds + 16384;            // [32][512] bf16, swizzled
    float* accx   = (float*)(h_lds + 16384);   // [2][4][16*64]  gx+bias
    int*   h_flag = (int*)(accx + 8192);       // poll flag

    const int wg   = blockIdx.x & 15;
    const int dir  = blockIdx.x >> 4;
    const int w    = threadIdx.x >> 6;
    const int lane = threadIdx.x & 63;
    const bool is_x = (w < 4);
    const int g    = w & 3;
    const int bcol = lane & 31;
    const int hi   = lane >> 5;
    const int hi8  = hi * 8;
    const int swz  = (bcol & 7) << 3;          // u16-unit swizzle
    const int tid4 = (w & 3) * 64 + lane;      // 0..255 within x- or h-group

    // A fragments, remapped rows (both x and h waves use the same mapping)
    bf16x8 afrag[32];
    {
        int rowA = lane & 31;
        const u16* Wm = Wc + (size_t)(dir * 2 + (is_x ? 0 : 1)) * (2048 * 512)
                      + (size_t)((rowA >> 3) * 512 + wg * 32 + g * 8 + (rowA & 7)) * 512 + hi8;
        #pragma unroll 32
        for (int kc = 0; kc < 32; kc++) afrag[kc] = *(const bf16x8*)(Wm + kc * 16);
    }
    float bias_r[16];
    if (is_x) {
        #pragma unroll 16
        for (int r = 0; r < 16; r++)
            bias_r[r] = biasC[dir * 2048 + (r >> 2) * 512 + wg * 32 + g * 8 + (r & 3) + 4 * hi];
    }
    if (threadIdx.x == 0) *h_flag = -1;

    float c_st[4] = {0.f, 0.f, 0.f, 0.f};
    bf16x8 xpre[8];

    __syncthreads();

    #pragma unroll 1
    for (int i = 0; i <= T_LEN + 1; ++i) {
        // ---------------- phase 1 ----------------
        if (is_x) {
            if (i == 0) {                       // prologue: direct-load tile 0
                const u16* src = xn + (size_t)(dir ? (T_LEN - 1) : 0) * (NB * DD);
                #pragma unroll 8
                for (int r = 0; r < 8; r++)
                    xpre[r] = *(const bf16x8*)(src + (tid4 + 256 * r) * 8);
            }
            if (i < T_LEN) {                    // commit tile i (prefetched) to LDS
                #pragma unroll 8
                for (int r = 0; r < 8; r++) {
                    int u = (tid4 + 256 * r) * 8;
                    int b = u >> 9, cu = u & 511;
                    *(bf16x8*)(xn_lds + b * 512 + (cu ^ ((b & 7) << 3))) = xpre[r];
                }
            }
        } else {
            if (i == 0) {                       // h(-1) = 0
                #pragma unroll 8
                for (int k = 0; k < 8; k++)
                    *(uint4*)(h_lds + tid4 * 64 + k * 8) = uint4{0, 0, 0, 0};
            } else if (i >= 2) {                // stage h(i-2)
                int sig = i - 2;
                if (g == 0) {
                    const int* sp = sent + dir * 64 + lane;
                    int guard = 600000;
                    while (true) {
                        int v = __hip_atomic_load(sp, __ATOMIC_RELAXED,
                                                  __HIP_MEMORY_SCOPE_AGENT);
                        if (__all(v >= sig) || --guard == 0) break;
                        __builtin_amdgcn_s_sleep(1);
                    }
                    __hip_atomic_store(h_flag, sig, __ATOMIC_RELEASE,
                                       __HIP_MEMORY_SCOPE_WORKGROUP);
                } else {
                    long guard = 50000000L;
                    while (__hip_atomic_load(h_flag, __ATOMIC_ACQUIRE,
                                             __HIP_MEMORY_SCOPE_WORKGROUP) < sig
                           && --guard > 0) {}
                }
                const u64* slot = data + (size_t)(dir * 2 + (sig & 1)) * 4096
                                + (size_t)tid4 * 16;
                u64 q[16];
                #pragma unroll 16
                for (int k = 0; k < 16; k++)
                    q[k] = __hip_atomic_load(slot + k, __ATOMIC_RELAXED,
                                             __HIP_MEMORY_SCOPE_AGENT);
                int j0 = (tid4 >> 1) * 4;       // u16 index of this lane's j-block
                #pragma unroll 16
                for (int k = 0; k < 16; k++) {
                    int b = (tid4 & 1) * 16 + k;
                    *(u64*)(h_lds + b * 512 + (j0 ^ ((b & 7) << 3))) = q[k];
                }
            }
        }
        __syncthreads();
        // ---------------- phase 3 ----------------
        if (is_x) {
            if (i + 1 < T_LEN) {                // prefetch tile i+1
                const u16* src = xn + (size_t)(dir ? (T_LEN - 2 - i) : (i + 1)) * (NB * DD);
                #pragma unroll 8
                for (int r = 0; r < 8; r++)
                    xpre[r] = *(const bf16x8*)(src + (tid4 + 256 * r) * 8);
            }
            if (i < T_LEN) {                    // gx(i)+bias -> accx[i&1]
                f32x16 a0, a1;
                #pragma unroll 16
                for (int r = 0; r < 16; r++) { a0[r] = 0.f; a1[r] = 0.f; }
                #pragma unroll 16
                for (int k2 = 0; k2 < 16; k2++) {
                    bf16x8 b0 = *(const bf16x8*)(xn_lds + bcol * 512 + (((2*k2  )*16 + hi8) ^ swz));
                    bf16x8 b1 = *(const bf16x8*)(xn_lds + bcol * 512 + (((2*k2+1)*16 + hi8) ^ swz));
                    a0 = __builtin_amdgcn_mfma_f32_32x32x16_bf16(afrag[2*k2],   b0, a0, 0, 0, 0);
                    a1 = __builtin_amdgcn_mfma_f32_32x32x16_bf16(afrag[2*k2+1], b1, a1, 0, 0, 0);
                }
                float* dst = accx + (i & 1) * 4096 + g * 1024;
                #pragma unroll 16
                for (int r = 0; r < 16; r++) dst[r * 64 + lane] = a0[r] + a1[r] + bias_r[r];
            }
            if (i >= 2) {                       // out/hist writes of h(i-2) from h_lds
                int sigma = i - 2;
                int tph = dir ? (T_LEN - 1 - sigma) : sigma;
                if (dir == 0) {
                    float* orow = out + (size_t)tph * (NB * HH);
                    #pragma unroll 4
                    for (int qq = 0; qq < 4; qq++) {
                        int idx = qq * 256 + tid4;          // 0..1023
                        int b2  = 2 * wg + (idx >> 9);
                        int j   = idx & 511;
                        int cu  = j & ~7, e = j & 7;
                        u16 hv = h_lds[b2 * 512 + ((cu ^ ((b2 & 7) << 3)) | e)];
                        orow[(size_t)b2 * HH + j] = __uint_as_float((u32)hv << 16);
                    }
                } else {
                    u16* hrow = hist + (size_t)tph * (NB * HH);
                    #pragma unroll 2
                    for (int qq = 0; qq < 2; qq++) {
                        int p  = qq * 256 + tid4;           // 0..511 (u32 pairs)
                        int b2 = 2 * wg + (p >> 8);
                        int j0 = (p * 2) & 511;
                        int cu = j0 & ~7, e0 = j0 & 7;
                        u32 v = *(const u32*)&h_lds[b2 * 512 + ((cu ^ ((b2 & 7) << 3)) | e0)];
                        *(u32*)&hrow[(size_t)b2 * HH + j0] = v;
                    }
                }
            }
        } else {
            if (i >= 1 && i <= T_LEN) {         // h-matvec + in-register gating + publish
                int sg = i - 1;
                f32x16 a0, a1;
                #pragma unroll 16
                for (int r = 0; r < 16; r++) { a0[r] = 0.f; a1[r] = 0.f; }
                #pragma unroll 16
                for (int k2 = 0; k2 < 16; k2++) {
                    bf16x8 b0 = *(const bf16x8*)(h_lds + bcol * 512 + (((2*k2  )*16 + hi8) ^ swz));
                    bf16x8 b1 = *(const bf16x8*)(h_lds + bcol * 512 + (((2*k2+1)*16 + hi8) ^ swz));
                    a0 = __builtin_amdgcn_mfma_f32_32x32x16_bf16(afrag[2*k2],   b0, a0, 0, 0, 0);
                    a1 = __builtin_amdgcn_mfma_f32_32x32x16_bf16(afrag[2*k2+1], b1, a1, 0, 0, 0);
                }
                const float* ax = accx + (sg & 1) * 4096 + g * 1024;
                float hv[4];
                #pragma unroll 4
                for (int m = 0; m < 4; m++) {
                    float gi = a0[m]      + a1[m]      + ax[(m     ) * 64 + lane];
                    float gf = a0[4 + m]  + a1[4 + m]  + ax[(4 + m ) * 64 + lane];
                    float gg_= a0[8 + m]  + a1[8 + m]  + ax[(8 + m ) * 64 + lane];
                    float go = a0[12 + m] + a1[12 + m] + ax[(12 + m) * 64 + lane];
                    float ig = fsig(gi), fg = fsig(gf), gv = ftanh(gg_), og = fsig(go);
                    float c = fg * c_st[m] + ig * gv;
                    c_st[m] = c;
                    hv[m] = og * ftanh(c);
                }
                u64 pk = (u64)f2bf(hv[0]) | ((u64)f2bf(hv[1]) << 16)
                       | ((u64)f2bf(hv[2]) << 32) | ((u64)f2bf(hv[3]) << 48);
                u64* dp = data + (size_t)(dir * 2 + (sg & 1)) * 4096
                        + (size_t)((wg * 8 + g * 2 + hi) * 32 + bcol);
                __hip_atomic_store(dp, pk, __ATOMIC_RELAXED, __HIP_MEMORY_SCOPE_AGENT);
                asm volatile("s_waitcnt vmcnt(0)" ::: "memory");
                if (lane == 0)
                    __hip_atomic_store(sent + dir * 64 + wg * 4 + g, sg,
                                       __ATOMIC_RELAXED, __HIP_MEMORY_SCOPE_AGENT);
            }
        }
        __syncthreads();
    }
}

extern "C" void kernel_launch(void* const* d_in, const int* in_sizes, int n_in,
                              void* d_out, int out_size, void* d_ws, size_t ws_size,
                              hipStream_t stream) {
    const float* x     = (const float*)d_in[0];
    const float* gamma = (const float*)d_in[1];
    const float* beta  = (const float*)d_in[2];
    const float* wih_f = (const float*)d_in[3];
    const float* whh_f = (const float*)d_in[4];
    const float* bih_f = (const float*)d_in[5];
    const float* bhh_f = (const float*)d_in[6];
    const float* wih_b = (const float*)d_in[7];
    const float* whh_b = (const float*)d_in[8];
    const float* bih_b = (const float*)d_in[9];
    const float* bhh_b = (const float*)d_in[10];
    float* out = (float*)d_out;

    u16*   xn    = (u16*)d_ws;                  // 32MB
    u16*   Wc    = xn + 16777216;               // 8MB
    float* biasC = (float*)(Wc + 4194304);      // 16KB
    u64*   data  = (u64*)(biasC + 4096);        // 16384 u64 = 128KB (2dir x 2slot x 4096)
    int*   sent  = (int*)(data + 16384);        // 128 ints
    u16*   hist  = (u16*)(sent + 128);          // 32MB

    (void)hipFuncSetAttribute((const void*)scan_kernel,
                              hipFuncAttributeMaxDynamicSharedMemorySize, SMEM_BYTES);

    ln_kernel<<<dim3(8192), dim3(256), 0, stream>>>(x, gamma, beta, xn);
    prep_kernel<<<dim3(4096), dim3(256), 0, stream>>>(wih_f, whh_f, bih_f, bhh_f,
                                                      wih_b, whh_b, bih_b, bhh_b,
                                                      Wc, biasC, data, sent);
    scan_kernel<<<dim3(32), dim3(512), SMEM_BYTES, stream>>>(xn, Wc, biasC, data,
                                                             sent, out, hist);
    add_kernel<<<dim3(2048), dim3(256), 0, stream>>>(out, hist);
}

// Round 9
// 6632.306 us; speedup vs baseline: 1.8171x; 1.1582x over previous
//
#include <hip/hip_runtime.h>
#include <hip/hip_bf16.h>

#define T_LEN 1024
#define NB    32
#define DD    512
#define HH    512
#define EPS_  1e-5f

typedef unsigned short u16;
typedef unsigned int   u32;
typedef unsigned long long u64;
typedef float  f32x16 __attribute__((ext_vector_type(16)));
typedef short  bf16x8 __attribute__((ext_vector_type(8)));

__device__ __forceinline__ u16 f2bf(float f) {
    union { float f; u32 u; } cv; cv.f = f;
    u32 r = cv.u + 0x7FFFu + ((cv.u >> 16) & 1u);   // RNE
    return (u16)(r >> 16);
}
__device__ __forceinline__ float fsig(float x) {
    return 1.0f / (1.0f + __expf(-x));
}
__device__ __forceinline__ float ftanh(float x) {
    float ax = fabsf(x);
    float e  = __expf(-2.0f * ax);
    float t  = (1.0f - e) / (1.0f + e);
    return copysignf(t, x);
}

// ---------------- LayerNorm: x[T,B,D] f32 -> xn bf16 ----------------
__global__ __launch_bounds__(256) void ln_kernel(const float* __restrict__ x,
                                                 const float* __restrict__ gamma,
                                                 const float* __restrict__ beta,
                                                 u16* __restrict__ xn) {
    int wave = threadIdx.x >> 6, lane = threadIdx.x & 63;
    long row = (long)blockIdx.x * 4 + wave;              // 0..T*B-1
    const float* xr = x + row * DD;
    int c0 = lane * 8;
    float4 v0 = *(const float4*)(xr + c0);
    float4 v1 = *(const float4*)(xr + c0 + 4);
    float s = v0.x+v0.y+v0.z+v0.w + v1.x+v1.y+v1.z+v1.w;
    float q = v0.x*v0.x+v0.y*v0.y+v0.z*v0.z+v0.w*v0.w
            + v1.x*v1.x+v1.y*v1.y+v1.z*v1.z+v1.w*v1.w;
    #pragma unroll
    for (int m = 1; m < 64; m <<= 1) { s += __shfl_xor(s, m); q += __shfl_xor(q, m); }
    float mu  = s * (1.0f / DD);
    float var = q * (1.0f / DD) - mu * mu;
    float rs  = rsqrtf(var + EPS_);
    float4 g0 = *(const float4*)(gamma + c0), g1 = *(const float4*)(gamma + c0 + 4);
    float4 b0 = *(const float4*)(beta  + c0), b1 = *(const float4*)(beta  + c0 + 4);
    float o[8];
    o[0]=(v0.x-mu)*rs*g0.x+b0.x; o[1]=(v0.y-mu)*rs*g0.y+b0.y;
    o[2]=(v0.z-mu)*rs*g0.z+b0.z; o[3]=(v0.w-mu)*rs*g0.w+b0.w;
    o[4]=(v1.x-mu)*rs*g1.x+b1.x; o[5]=(v1.y-mu)*rs*g1.y+b1.y;
    o[6]=(v1.z-mu)*rs*g1.z+b1.z; o[7]=(v1.w-mu)*rs*g1.w+b1.w;
    uint4 pk;
    pk.x = (u32)f2bf(o[0]) | ((u32)f2bf(o[1]) << 16);
    pk.y = (u32)f2bf(o[2]) | ((u32)f2bf(o[3]) << 16);
    pk.z = (u32)f2bf(o[4]) | ((u32)f2bf(o[5]) << 16);
    pk.w = (u32)f2bf(o[6]) | ((u32)f2bf(o[7]) << 16);
    *(uint4*)(xn + row * DD + c0) = pk;
}

// ---------------- prep: W->bf16, bias combine, init data+sentinels ----------------
__global__ __launch_bounds__(256) void prep_kernel(
        const float* __restrict__ wih_f, const float* __restrict__ whh_f,
        const float* __restrict__ bih_f, const float* __restrict__ bhh_f,
        const float* __restrict__ wih_b, const float* __restrict__ whh_b,
        const float* __restrict__ bih_b, const float* __restrict__ bhh_b,
        u16* __restrict__ Wc, float* __restrict__ biasC,
        u64* __restrict__ data, int* __restrict__ sent) {
    long i0 = (long)blockIdx.x * 256 + threadIdx.x;
    long stride = (long)gridDim.x * 256;
    for (long idx = i0; idx < 4194304L; idx += stride) {
        int m = (int)(idx >> 20); int off = (int)(idx & 1048575L);
        const float* src = (m == 0) ? wih_f : (m == 1) ? whh_f : (m == 2) ? wih_b : whh_b;
        Wc[idx] = f2bf(src[off]);
        if (idx < 4096L) {
            int d = (int)(idx >> 11), n = (int)(idx & 2047L);
            biasC[idx] = d ? (bih_b[n] + bhh_b[n]) : (bih_f[n] + bhh_f[n]);
        }
        if (idx < 16384L) data[idx] = 0;                   // h = 0
        if (idx < 128L)   sent[idx] = -1;                  // MUST reset each call (replays)
    }
}

// ---------------- epilogue: out += bf16(hist_b) ----------------
__global__ __launch_bounds__(256) void add_kernel(float* __restrict__ out,
                                                  const u16* __restrict__ hist) {
    long i0 = (long)blockIdx.x * 256 + threadIdx.x;
    long stride = (long)gridDim.x * 256;
    const ushort4* h4 = (const ushort4*)hist;
    float4* o4 = (float4*)out;
    for (long i = i0; i < 4194304L; i += stride) {
        float4 o = o4[i];
        ushort4 h = h4[i];
        o.x += __uint_as_float((u32)h.x << 16);
        o.y += __uint_as_float((u32)h.y << 16);
        o.z += __uint_as_float((u32)h.z << 16);
        o.w += __uint_as_float((u32)h.w << 16);
        o4[i] = o;
    }
}

// ---------------- persistent bidirectional LSTM scan ----------------
// 32 blocks: block = (dir<<4)|wg. 8 waves: w0-3 x-waves, w4-7 h-waves.
// R7 skeleton (proven): gate-in-register h-waves, sentinel protocol, agent-scope
// MALL exchange. R8 deltas: (1) staging bulk-read is COALESCED (instr n: lane tid4
// loads packets n*512+2*tid4 -> 1KB contiguous per wave per instr; plain loads with
// sc0 sc1 cache-bypass -- race-free because data is quiescent after the sentinel);
// (2) xn prefetch issued at end of phase 1 (2us of cover); (3) s_sleep in LDS spin.
#define SMEM_BYTES 98320
__global__ __launch_bounds__(512, 2) void scan_kernel(
        const u16* __restrict__ xn, const u16* __restrict__ Wc,
        const float* __restrict__ biasC, u64* __restrict__ data,
        int* __restrict__ sent, float* __restrict__ out, u16* __restrict__ hist) {
    extern __shared__ char smem_raw[];
    u16*   xn_lds = (u16*)smem_raw;            // [32][512] bf16, swizzled
    u16*   h_lds  = xn_lds + 16384;            // [32][512] bf16, swizzled
    float* accx   = (float*)(h_lds + 16384);   // [2][4][16*64]  gx+bias
    int*   h_flag = (int*)(accx + 8192);       // poll flag

    const int wg   = blockIdx.x & 15;
    const int dir  = blockIdx.x >> 4;
    const int w    = threadIdx.x >> 6;
    const int lane = threadIdx.x & 63;
    const bool is_x = (w < 4);
    const int g    = w & 3;
    const int bcol = lane & 31;
    const int hi   = lane >> 5;
    const int hi8  = hi * 8;
    const int swz  = (bcol & 7) << 3;          // u16-unit swizzle
    const int tid4 = (w & 3) * 64 + lane;      // 0..255 within x- or h-group

    // A fragments, remapped rows: row r <-> W row (r>>3)*512 + wg*32 + g*8 + (r&7)
    bf16x8 afrag[32];
    {
        int rowA = lane & 31;
        const u16* Wm = Wc + (size_t)(dir * 2 + (is_x ? 0 : 1)) * (2048 * 512)
                      + (size_t)((rowA >> 3) * 512 + wg * 32 + g * 8 + (rowA & 7)) * 512 + hi8;
        #pragma unroll 32
        for (int kc = 0; kc < 32; kc++) afrag[kc] = *(const bf16x8*)(Wm + kc * 16);
    }
    float bias_r[16];
    if (is_x) {
        #pragma unroll 16
        for (int r = 0; r < 16; r++)
            bias_r[r] = biasC[dir * 2048 + (r >> 2) * 512 + wg * 32 + g * 8 + (r & 3) + 4 * hi];
    }
    if (threadIdx.x == 0) *h_flag = -1;

    float c_st[4] = {0.f, 0.f, 0.f, 0.f};
    bf16x8 xpre[8];

    __syncthreads();

    #pragma unroll 1
    for (int i = 0; i <= T_LEN + 1; ++i) {
        // ---------------- phase 1 ----------------
        if (is_x) {
            if (i == 0) {                       // prologue: direct-load tile 0
                const u16* src = xn + (size_t)(dir ? (T_LEN - 1) : 0) * (NB * DD);
                #pragma unroll 8
                for (int r = 0; r < 8; r++)
                    xpre[r] = *(const bf16x8*)(src + (tid4 + 256 * r) * 8);
            }
            if (i < T_LEN) {                    // commit tile i (prefetched) to LDS
                #pragma unroll 8
                for (int r = 0; r < 8; r++) {
                    int u = (tid4 + 256 * r) * 8;
                    int b = u >> 9, cu = u & 511;
                    *(bf16x8*)(xn_lds + b * 512 + (cu ^ ((b & 7) << 3))) = xpre[r];
                }
            }
            if (i + 1 < T_LEN) {                // issue prefetch for tile i+1 (2us cover)
                const u16* src = xn + (size_t)(dir ? (T_LEN - 2 - i) : (i + 1)) * (NB * DD);
                #pragma unroll 8
                for (int r = 0; r < 8; r++)
                    xpre[r] = *(const bf16x8*)(src + (tid4 + 256 * r) * 8);
            }
        } else {
            if (i == 0) {                       // h(-1) = 0
                #pragma unroll 8
                for (int k = 0; k < 8; k++)
                    *(uint4*)(h_lds + tid4 * 64 + k * 8) = uint4{0, 0, 0, 0};
            } else if (i >= 2) {                // stage h(i-2)
                int sig = i - 2;
                if (g == 0) {
                    const int* sp = sent + dir * 64 + lane;
                    int guard = 600000;
                    while (true) {
                        int v = __hip_atomic_load(sp, __ATOMIC_RELAXED,
                                                  __HIP_MEMORY_SCOPE_AGENT);
                        if (__all(v >= sig) || --guard == 0) break;
                        __builtin_amdgcn_s_sleep(1);
                    }
                    __hip_atomic_store(h_flag, sig, __ATOMIC_RELEASE,
                                       __HIP_MEMORY_SCOPE_WORKGROUP);
                } else {
                    long guard = 50000000L;
                    while (__hip_atomic_load(h_flag, __ATOMIC_ACQUIRE,
                                             __HIP_MEMORY_SCOPE_WORKGROUP) < sig
                           && --guard > 0)
                        __builtin_amdgcn_s_sleep(1);
                }
                // Coalesced bulk read: instr n -> lane tid4 loads packets n*512 + 2*tid4
                // (16B). Plain loads + sc0 sc1 (cache bypass); data quiescent post-sentinel.
                const char* bp = (const char*)(data + (size_t)(dir * 2 + (sig & 1)) * 4096)
                               + (size_t)tid4 * 16;
                uint4 dq[8];
                #pragma unroll 8
                for (int n = 0; n < 8; n++) {
                    const char* ap = bp + n * 4096;
                    uint4 v;
                    asm volatile("global_load_dwordx4 %0, %1, off sc0 sc1"
                                 : "=&v"(v) : "v"(ap));
                    dq[n] = v;
                }
                asm volatile("s_waitcnt vmcnt(0)" ::: "memory");
                __builtin_amdgcn_sched_barrier(0);
                // unpack: packet p0=n*512+2*tid4 -> b0=2*(tid4&15), j4=n*16+(tid4>>4)
                int b0  = 2 * (tid4 & 15);
                int jb  = 4 * (tid4 >> 4);
                int sw0 = (b0 & 7) << 3;
                int sw1 = ((b0 + 1) & 7) << 3;
                u16* r0 = h_lds + b0 * 512;
                u16* r1 = r0 + 512;
                #pragma unroll 8
                for (int n = 0; n < 8; n++) {
                    int j = 64 * n + jb;
                    *(u64*)(r0 + (j ^ sw0)) = ((const u64*)&dq[n])[0];
                    *(u64*)(r1 + (j ^ sw1)) = ((const u64*)&dq[n])[1];
                }
            }
        }
        __syncthreads();
        // ---------------- phase 3 ----------------
        if (is_x) {
            if (i < T_LEN) {                    // gx(i)+bias -> accx[i&1]
                f32x16 a0, a1;
                #pragma unroll 16
                for (int r = 0; r < 16; r++) { a0[r] = 0.f; a1[r] = 0.f; }
                #pragma unroll 16
                for (int k2 = 0; k2 < 16; k2++) {
                    bf16x8 b0 = *(const bf16x8*)(xn_lds + bcol * 512 + (((2*k2  )*16 + hi8) ^ swz));
                    bf16x8 b1 = *(const bf16x8*)(xn_lds + bcol * 512 + (((2*k2+1)*16 + hi8) ^ swz));
                    a0 = __builtin_amdgcn_mfma_f32_32x32x16_bf16(afrag[2*k2],   b0, a0, 0, 0, 0);
                    a1 = __builtin_amdgcn_mfma_f32_32x32x16_bf16(afrag[2*k2+1], b1, a1, 0, 0, 0);
                }
                float* dst = accx + (i & 1) * 4096 + g * 1024;
                #pragma unroll 16
                for (int r = 0; r < 16; r++) dst[r * 64 + lane] = a0[r] + a1[r] + bias_r[r];
            }
            if (i >= 2) {                       // out/hist writes of h(i-2) from h_lds
                int sigma = i - 2;
                int tph = dir ? (T_LEN - 1 - sigma) : sigma;
                if (dir == 0) {
                    float* orow = out + (size_t)tph * (NB * HH);
                    #pragma unroll 4
                    for (int qq = 0; qq < 4; qq++) {
                        int idx = qq * 256 + tid4;          // 0..1023
                        int b2  = 2 * wg + (idx >> 9);
                        int j   = idx & 511;
                        int cu  = j & ~7, e = j & 7;
                        u16 hv = h_lds[b2 * 512 + ((cu ^ ((b2 & 7) << 3)) | e)];
                        orow[(size_t)b2 * HH + j] = __uint_as_float((u32)hv << 16);
                    }
                } else {
                    u16* hrow = hist + (size_t)tph * (NB * HH);
                    #pragma unroll 2
                    for (int qq = 0; qq < 2; qq++) {
                        int p  = qq * 256 + tid4;           // 0..511 (u32 pairs)
                        int b2 = 2 * wg + (p >> 8);
                        int j0 = (p * 2) & 511;
                        int cu = j0 & ~7, e0 = j0 & 7;
                        u32 v = *(const u32*)&h_lds[b2 * 512 + ((cu ^ ((b2 & 7) << 3)) | e0)];
                        *(u32*)&hrow[(size_t)b2 * HH + j0] = v;
                    }
                }
            }
        } else {
            if (i >= 1 && i <= T_LEN) {         // h-matvec + in-register gating + publish
                int sg = i - 1;
                f32x16 a0, a1;
                #pragma unroll 16
                for (int r = 0; r < 16; r++) { a0[r] = 0.f; a1[r] = 0.f; }
                #pragma unroll 16
                for (int k2 = 0; k2 < 16; k2++) {
                    bf16x8 b0 = *(const bf16x8*)(h_lds + bcol * 512 + (((2*k2  )*16 + hi8) ^ swz));
                    bf16x8 b1 = *(const bf16x8*)(h_lds + bcol * 512 + (((2*k2+1)*16 + hi8) ^ swz));
                    a0 = __builtin_amdgcn_mfma_f32_32x32x16_bf16(afrag[2*k2],   b0, a0, 0, 0, 0);
                    a1 = __builtin_amdgcn_mfma_f32_32x32x16_bf16(afrag[2*k2+1], b1, a1, 0, 0, 0);
                }
                const float* ax = accx + (sg & 1) * 4096 + g * 1024;
                float hv[4];
                #pragma unroll 4
                for (int m = 0; m < 4; m++) {
                    float gi = a0[m]      + a1[m]      + ax[(m     ) * 64 + lane];
                    float gf = a0[4 + m]  + a1[4 + m]  + ax[(4 + m ) * 64 + lane];
                    float gg_= a0[8 + m]  + a1[8 + m]  + ax[(8 + m ) * 64 + lane];
                    float go = a0[12 + m] + a1[12 + m] + ax[(12 + m) * 64 + lane];
                    float ig = fsig(gi), fg = fsig(gf), gv = ftanh(gg_), og = fsig(go);
                    float c = fg * c_st[m] + ig * gv;
                    c_st[m] = c;
                    hv[m] = og * ftanh(c);
                }
                u64 pk = (u64)f2bf(hv[0]) | ((u64)f2bf(hv[1]) << 16)
                       | ((u64)f2bf(hv[2]) << 32) | ((u64)f2bf(hv[3]) << 48);
                u64* dp = data + (size_t)(dir * 2 + (sg & 1)) * 4096
                        + (size_t)((wg * 8 + g * 2 + hi) * 32 + bcol);
                __hip_atomic_store(dp, pk, __ATOMIC_RELAXED, __HIP_MEMORY_SCOPE_AGENT);
                asm volatile("s_waitcnt vmcnt(0)" ::: "memory");
                if (lane == 0)
                    __hip_atomic_store(sent + dir * 64 + wg * 4 + g, sg,
                                       __ATOMIC_RELAXED, __HIP_MEMORY_SCOPE_AGENT);
            }
        }
        __syncthreads();
    }
}

extern "C" void kernel_launch(void* const* d_in, const int* in_sizes, int n_in,
                              void* d_out, int out_size, void* d_ws, size_t ws_size,
                              hipStream_t stream) {
    const float* x     = (const float*)d_in[0];
    const float* gamma = (const float*)d_in[1];
    const float* beta  = (const float*)d_in[2];
    const float* wih_f = (const float*)d_in[3];
    const float* whh_f = (const float*)d_in[4];
    const float* bih_f = (const float*)d_in[5];
    const float* bhh_f = (const float*)d_in[6];
    const float* wih_b = (const float*)d_in[7];
    const float* whh_b = (const float*)d_in[8];
    const float* bih_b = (const float*)d_in[9];
    const float* bhh_b = (const float*)d_in[10];
    float* out = (float*)d_out;

    u16*   xn    = (u16*)d_ws;                  // 32MB
    u16*   Wc    = xn + 16777216;               // 8MB
    float* biasC = (float*)(Wc + 4194304);      // 16KB
    u64*   data  = (u64*)(biasC + 4096);        // 16384 u64 = 128KB (2dir x 2slot x 4096)
    int*   sent  = (int*)(data + 16384);        // 128 ints
    u16*   hist  = (u16*)(sent + 128);          // 32MB

    (void)hipFuncSetAttribute((const void*)scan_kernel,
                              hipFuncAttributeMaxDynamicSharedMemorySize, SMEM_BYTES);

    ln_kernel<<<dim3(8192), dim3(256), 0, stream>>>(x, gamma, beta, xn);
    prep_kernel<<<dim3(4096), dim3(256), 0, stream>>>(wih_f, whh_f, bih_f, bhh_f,
                                                      wih_b, whh_b, bih_b, bhh_b,
                                                      Wc, biasC, data, sent);
    scan_kernel<<<dim3(32), dim3(512), SMEM_BYTES, stream>>>(xn, Wc, biasC, data,
                                                             sent, out, hist);
    add_kernel<<<dim3(2048), dim3(256), 0, stream>>>(out, hist);
}